// Round 1
// baseline (676.581 us; speedup 1.0000x reference)
//
#include <hip/hip_runtime.h>
#include <hip/hip_bf16.h>

// ---------------- problem constants ----------------
constexpr long NN = 20000;   // nodes
constexpr long NE = 160000;  // edges
constexpr long BB = 200;     // graphs
constexpr long TT = 8;       // taus
constexpr long GN = 100;     // nodes per graph

// ---------------- ws layout (f32 element offsets) ----------------
constexpr long O_FLAG = 0;                                      // int mode flag
constexpr long O_X    = 16;                 constexpr long N_X   = 40000;
constexpr long O_TAU  = O_X + N_X;          constexpr long N_TAU = 1600;
constexpr long O_W1   = O_TAU + N_TAU;      constexpr long N_W1  = 4096;
constexpr long O_Q1   = O_W1 + N_W1;        constexpr long N_Q   = 2048;
constexpr long O_K1   = O_Q1 + N_Q;
constexpr long O_B1   = O_K1 + N_Q;         constexpr long N_B   = 128;
constexpr long O_W2   = O_B1 + N_B;         constexpr long N_W2  = 262144;
constexpr long O_Q2   = O_W2 + N_W2;
constexpr long O_K2   = O_Q2 + N_Q;
constexpr long O_B2   = O_K2 + N_Q;
constexpr long O_CW   = O_B2 + N_B;         constexpr long N_CW  = 8192;
constexpr long O_CB   = O_CW + N_CW;
constexpr long O_F1W  = O_CB + N_B;         constexpr long N_FW  = 16384;
constexpr long O_F1B  = O_F1W + N_FW;
constexpr long O_F1SW = O_F1B + N_B;
constexpr long O_F1SB = O_F1SW + N_FW;
constexpr long O_F1EW = O_F1SB + N_B;
constexpr long O_F1EB = O_F1EW + N_FW;
constexpr long O_F2W  = O_F1EB + N_B;
constexpr long O_F2B  = O_F2W + N_FW;
constexpr long O_F2SW = O_F2B + N_B;
constexpr long O_F2SB = O_F2SW + N_FW;
constexpr long O_F2EW = O_F2SB + N_B;
constexpr long O_F2EB = O_F2EW + N_FW;
constexpr long O_AW   = O_F2EB + N_B;       constexpr long N_AW  = 1280;
constexpr long O_AB   = O_AW + N_AW;        constexpr long N_AB  = 16;  // 10 used
constexpr long O_ASW  = O_AB + N_AB;
constexpr long O_ASB  = O_ASW + N_AW;
constexpr long O_AEW  = O_ASB + N_AB;
constexpr long O_AEB  = O_AEW + N_AW;
constexpr long O_VW   = O_AEB + N_AB;       constexpr long N_VW  = 128;
constexpr long O_VB   = O_VW + N_VW;        constexpr long N_VB  = 16;  // 1 used
constexpr long O_VSW  = O_VB + N_VB;
constexpr long O_VSB  = O_VSW + N_VW;
constexpr long O_VEW  = O_VSB + N_VB;
constexpr long O_VEB  = O_VEW + N_VW;
// derived
constexpr long O_WQ1  = O_VEB + N_VB;       // [4][2][4] = 32
constexpr long O_WK1  = O_WQ1 + 32;
constexpr long O_WQ2  = O_WK1 + 32;         // [4][128][4] = 2048
constexpr long O_WK2  = O_WQ2 + 2048;
constexpr long O_CF1W = O_WK2 + 2048;       // combined noisy weights
constexpr long O_CF1B = O_CF1W + N_FW;
constexpr long O_CF2W = O_CF1B + N_B;
constexpr long O_CF2B = O_CF2W + N_FW;
constexpr long O_CAW  = O_CF2B + N_B;
constexpr long O_CAB  = O_CAW + N_AW;
constexpr long O_CVW  = O_CAB + N_AB;
constexpr long O_CVB  = O_CVW + N_VW;
constexpr long O_AL1  = O_CVB + N_VB;       // [E][4] logits -> exp
constexpr long O_AL2  = O_AL1 + NE*4;
constexpr long O_H1   = O_AL2 + NE*4;       // [N][128]
constexpr long O_H2   = O_H1 + NN*128;
constexpr long O_G    = O_H2 + NN*128;      // [200][128]
constexpr long O_Z0   = O_G + BB*128;       // [1600][128]
constexpr long O_Z1   = O_Z0 + BB*TT*128;
constexpr long O_Z2   = O_Z1 + BB*TT*128;
// zero-init region (contiguous)
constexpr long O_AGG1 = O_Z2 + BB*TT*128;   // [N][128]
constexpr long O_AGG2 = O_AGG1 + NN*128;
constexpr long O_DEN1 = O_AGG2 + NN*128;    // [N][4]
constexpr long O_DEN2 = O_DEN1 + NN*4;
constexpr long O_AMAX1= O_DEN2 + NN*4;      // [N][4] ordered-uint keys
constexpr long O_AMAX2= O_AMAX1 + NN*4;
constexpr long ZERO_CNT = (O_AMAX2 + NN*4) - O_AGG1;
// bf16 xw2 table [N][4][512] (viewed as u16)
constexpr long O_XW2  = O_AMAX2 + NN*4;
constexpr long O_END_TABLE = O_XW2 + (NN*4*512)/2;   // f32 slots for bf16 table
constexpr long O_END_NOTAB = O_XW2;

#define DEVFN __device__ __forceinline__

DEVFN float selu_f(float x){ return 1.0507009873554805f * (x > 0.f ? x : 1.6732632423543772f * expm1f(x)); }
DEVFN float lrelu_f(float x){ return x >= 0.f ? x : 0.2f * x; }
DEVFN unsigned fkey(float x){ unsigned b = __float_as_uint(x); return (b & 0x80000000u) ? ~b : (b | 0x80000000u); }
DEVFN float fkey_inv(unsigned k){ unsigned b = (k & 0x80000000u) ? (k ^ 0x80000000u) : ~k; return __uint_as_float(b); }

// ---------------- mode detection ----------------
__global__ void k_detect(const unsigned short* taus_u16, int* flag){
    if (threadIdx.x == 0){
        int bf = 1;
        for (int i = 0; i < 128; i++){
            if (taus_u16[i] > 0x3F80u){ bf = 0; break; }   // bf16 uniform[0,1] never exceeds 1.0
        }
        *flag = bf;
    }
}

// ---------------- convert all float inputs to f32 in ws ----------------
struct ConvArgs { const void* src[38]; long off[38]; int n[38]; };

__global__ void k_convert(ConvArgs a, float* ws){
    int arr = blockIdx.y;
    long off = a.off[arr];
    if (off < 0) return;
    const void* s = a.src[arr];
    int n = a.n[arr];
    int bf = ((const int*)ws)[0];
    for (int i = blockIdx.x*blockDim.x + threadIdx.x; i < n; i += gridDim.x*blockDim.x){
        float v;
        if (bf){ unsigned short u = ((const unsigned short*)s)[i]; v = __uint_as_float(((unsigned)u) << 16); }
        else   { v = ((const float*)s)[i]; }
        ws[off + i] = v;
    }
}

// ---------------- fold W@q / W@k ----------------
__global__ void k_fold(float* ws){
    int task = blockIdx.y;
    int idx = blockIdx.x*blockDim.x + threadIdx.x;
    if (task < 2){                       // layer1: [r*2+i][h], 32 outputs, K=512
        if (idx >= 32) return;
        int h = idx & 3, ri = idx >> 2;
        const float* W = ws + O_W1 + (long)ri*512;
        const float* Q = ws + (task == 0 ? O_Q1 : O_K1);
        float s = 0.f;
        for (int o = 0; o < 512; o++) s += W[o] * Q[o*4 + h];
        ws[(task == 0 ? O_WQ1 : O_WK1) + idx] = s;
    } else {                             // layer2: [r*128+i][h], 2048 outputs, K=512
        if (idx >= 2048) return;
        int h = idx & 3, ri = idx >> 2;
        const float* W = ws + O_W2 + (long)ri*512;
        const float* Q = ws + (task == 2 ? O_Q2 : O_K2);
        float s = 0.f;
        for (int o = 0; o < 512; o++) s += W[o] * Q[o*4 + h];
        ws[(task == 2 ? O_WQ2 : O_WK2) + idx] = s;
    }
}

// ---------------- combine noisy weights: w + sw*ew, b + sb*eb ----------------
__global__ void k_noisy(float* ws){
    const long tw[8] = {O_F1W,O_F2W,O_AW,O_VW, O_F1B,O_F2B,O_AB,O_VB};
    const long ts[8] = {O_F1SW,O_F2SW,O_ASW,O_VSW, O_F1SB,O_F2SB,O_ASB,O_VSB};
    const long te[8] = {O_F1EW,O_F2EW,O_AEW,O_VEW, O_F1EB,O_F2EB,O_AEB,O_VEB};
    const long td[8] = {O_CF1W,O_CF2W,O_CAW,O_CVW, O_CF1B,O_CF2B,O_CAB,O_CVB};
    const int  tn[8] = {16384,16384,1280,128, 128,128,10,1};
    int t = blockIdx.y;
    for (int i = blockIdx.x*blockDim.x + threadIdx.x; i < tn[t]; i += gridDim.x*blockDim.x)
        ws[td[t] + i] = ws[tw[t] + i] + ws[ts[t] + i]*ws[te[t] + i];
}

// ---------------- layer 1: attention logits + segment max ----------------
__global__ void k_alpha1(const int* ei, const int* et, float* ws){
    long e = (long)blockIdx.x*blockDim.x + threadIdx.x;
    if (e >= NE) return;
    int src = ei[e], dst = ei[NE + e], rt = et[e];
    float xs0 = ws[O_X + (long)src*2], xs1 = ws[O_X + (long)src*2 + 1];
    float xd0 = ws[O_X + (long)dst*2], xd1 = ws[O_X + (long)dst*2 + 1];
    const float* Wq = ws + O_WQ1 + rt*8;   // [i*4+h]
    const float* Wk = ws + O_WK1 + rt*8;
    unsigned* am = (unsigned*)(ws + O_AMAX1);
    #pragma unroll
    for (int h = 0; h < 4; h++){
        float a = xd0*Wq[h] + xd1*Wq[4+h] + xs0*Wk[h] + xs1*Wk[4+h];
        a = lrelu_f(a);
        ws[O_AL1 + e*4 + h] = a;
        atomicMax(&am[(long)dst*4 + h], fkey(a));
    }
}

// ---------------- shared: exp(alpha - amax) + segment sum ----------------
__global__ void k_ex(const int* ei, float* ws, long o_al, long o_amax, long o_den){
    long e = (long)blockIdx.x*blockDim.x + threadIdx.x;
    if (e >= NE) return;
    int dst = ei[NE + e];
    const unsigned* am = (const unsigned*)(ws + o_amax);
    #pragma unroll
    for (int h = 0; h < 4; h++){
        float mx = fkey_inv(am[(long)dst*4 + h]);
        float ex = expf(ws[o_al + e*4 + h] - mx);
        ws[o_al + e*4 + h] = ex;
        atomicAdd(&ws[o_den + (long)dst*4 + h], ex);
    }
}

// ---------------- layer 1 messages: head-combined 128-float atomic add ----------------
__global__ void k_msg1(const int* ei, const int* et, float* ws){
    int le = threadIdx.x >> 7, d = threadIdx.x & 127;
    long e = (long)blockIdx.x*2 + le;
    if (e >= NE) return;
    int src = ei[e], dst = ei[NE + e], rt = et[e];
    float xs0 = ws[O_X + (long)src*2], xs1 = ws[O_X + (long)src*2 + 1];
    float v = 0.f;
    #pragma unroll
    for (int h = 0; h < 4; h++){
        float a = ws[O_AL1 + e*4 + h] / ws[O_DEN1 + (long)dst*4 + h];
        const float* W = ws + O_W1 + (long)(rt*2)*512 + h*128 + d;   // i=0 row; +512 -> i=1
        v += a * (xs0*W[0] + xs1*W[512]);
    }
    atomicAdd(&ws[O_AGG1 + (long)dst*128 + d], 0.25f * v);
}

// ---------------- h = selu(agg + b) ----------------
__global__ void k_h(float* ws, long o_agg, long o_b, long o_dst){
    long i = (long)blockIdx.x*blockDim.x + threadIdx.x;
    if (i >= NN*128) return;
    int d = (int)(i & 127);
    ws[o_dst + i] = selu_f(ws[o_agg + i] + ws[o_b + d]);
}

// ---------------- xw2 = h1 @ W2  (bf16 table, 16 nodes/block) ----------------
__global__ void k_xw2(float* ws){
    __shared__ float hrow[16][128];
    long nb = (long)blockIdx.x * 16;
    int t = threadIdx.x;
    for (int k = 0; k < 8; k++){
        int idx = k*256 + t;
        hrow[idx >> 7][idx & 127] = ws[O_H1 + nb*128 + idx];
    }
    __syncthreads();
    __hip_bfloat16* xb = (__hip_bfloat16*)(ws + O_XW2);
    for (int k = 0; k < 8; k++){
        int o = k*256 + t;                  // 0..2047
        int r = o >> 9, oi = o & 511;
        const float* W = ws + O_W2 + (long)r*65536 + oi;   // stride 512 over i
        float acc[16];
        #pragma unroll
        for (int j = 0; j < 16; j++) acc[j] = 0.f;
        for (int i = 0; i < 128; i++){
            float w = W[(long)i*512];
            #pragma unroll
            for (int j = 0; j < 16; j++) acc[j] += hrow[j][i]*w;
        }
        for (int j = 0; j < 16; j++) xb[(nb + j)*2048 + o] = __float2bfloat16(acc[j]);
    }
}

// ---------------- layer 2 logits via folded Wq2/Wk2 ----------------
__global__ void k_alpha2(const int* ei, const int* et, float* ws){
    long e = (long)blockIdx.x*blockDim.x + threadIdx.x;
    if (e >= NE) return;
    int src = ei[e], dst = ei[NE + e], rt = et[e];
    const float4* hs4 = (const float4*)(ws + O_H1 + (long)src*128);
    const float4* hd4 = (const float4*)(ws + O_H1 + (long)dst*128);
    const float* Wq = ws + O_WQ2 + (long)rt*512;   // [i*4+h]
    const float* Wk = ws + O_WK2 + (long)rt*512;
    float a[4] = {0.f,0.f,0.f,0.f};
    for (int i0 = 0; i0 < 32; i0++){
        float4 s4 = hs4[i0], d4 = hd4[i0];
        const float* wq = Wq + i0*16;
        const float* wk = Wk + i0*16;
        #pragma unroll
        for (int h = 0; h < 4; h++){
            a[h] += d4.x*wq[h] + d4.y*wq[4+h] + d4.z*wq[8+h] + d4.w*wq[12+h]
                  + s4.x*wk[h] + s4.y*wk[4+h] + s4.z*wk[8+h] + s4.w*wk[12+h];
        }
    }
    unsigned* am = (unsigned*)(ws + O_AMAX2);
    #pragma unroll
    for (int h = 0; h < 4; h++){
        float v = lrelu_f(a[h]);
        ws[O_AL2 + e*4 + h] = v;
        atomicMax(&am[(long)dst*4 + h], fkey(v));
    }
}

// ---------------- layer 2 messages via bf16 table ----------------
__global__ void k_msg2(const int* ei, const int* et, float* ws){
    int le = threadIdx.x >> 7, d = threadIdx.x & 127;
    long e = (long)blockIdx.x*2 + le;
    if (e >= NE) return;
    int src = ei[e], dst = ei[NE + e], rt = et[e];
    const __hip_bfloat16* xr = (const __hip_bfloat16*)(ws + O_XW2) + ((long)src*4 + rt)*512;
    float v = 0.f;
    #pragma unroll
    for (int h = 0; h < 4; h++){
        float a = ws[O_AL2 + e*4 + h] / ws[O_DEN2 + (long)dst*4 + h];
        v += a * __bfloat162float(xr[h*128 + d]);
    }
    atomicAdd(&ws[O_AGG2 + (long)dst*128 + d], 0.25f * v);
}

// ---------------- layer 2 messages, no-table fallback ----------------
__global__ void k_msg2_direct(const int* ei, const int* et, float* ws){
    __shared__ float hsrow[2][128];
    __shared__ float ash[2][4];
    int le = threadIdx.x >> 7, d = threadIdx.x & 127;
    long e = (long)blockIdx.x*2 + le;
    int src = 0, dst = 0, rt = 0;
    bool ok = (e < NE);
    if (ok){
        src = ei[e]; dst = ei[NE + e]; rt = et[e];
        hsrow[le][d] = ws[O_H1 + (long)src*128 + d];
        if (d < 4) ash[le][d] = ws[O_AL2 + e*4 + d] / ws[O_DEN2 + (long)dst*4 + d];
    }
    __syncthreads();
    if (!ok) return;
    float a0 = ash[le][0]*0.25f, a1 = ash[le][1]*0.25f, a2 = ash[le][2]*0.25f, a3 = ash[le][3]*0.25f;
    const float* W = ws + O_W2 + (long)rt*65536 + d;
    float v = 0.f;
    for (int i = 0; i < 128; i++){
        const float* Wi = W + (long)i*512;
        v += hsrow[le][i] * (a0*Wi[0] + a1*Wi[128] + a2*Wi[256] + a3*Wi[384]);
    }
    atomicAdd(&ws[O_AGG2 + (long)dst*128 + d], v);
}

// ---------------- global add pool ----------------
__global__ void k_pool(float* ws){
    int b = blockIdx.x, d = threadIdx.x;
    float s = 0.f;
    for (int j = 0; j < GN; j++) s += ws[O_H2 + ((long)b*GN + j)*128 + d];
    ws[O_G + (long)b*128 + d] = s;
}

// ---------------- cosine embedding + z = g * relu(cos @ cw^T + cb) ----------------
__global__ void k_cosz(float* ws){
    __shared__ float cs[64];
    int bt = blockIdx.x, t = threadIdx.x;
    if (t < 64){
        float tau = ws[O_TAU + bt];
        cs[t] = cosf(tau * (3.14159265358979323846f * (float)(t + 1)));
    }
    __syncthreads();
    int b = bt >> 3;   // T = 8
    const float* cw = ws + O_CW + (long)t*64;
    float s = ws[O_CB + t];
    for (int c = 0; c < 64; c++) s += cs[c]*cw[c];
    s = fmaxf(s, 0.f);
    ws[O_Z0 + (long)bt*128 + t] = ws[O_G + (long)b*128 + t] * s;
}

// ---------------- noisy FF layer: dst = selu(src @ W^T + B) ----------------
__global__ void k_ff(float* ws, long o_src, long o_w, long o_b, long o_dst){
    __shared__ float row[128];
    int bt = blockIdx.x, t = threadIdx.x;
    row[t] = ws[o_src + (long)bt*128 + t];
    __syncthreads();
    const float* W = ws + o_w + (long)t*128;
    float s = ws[o_b + t];
    for (int i = 0; i < 128; i++) s += row[i]*W[i];
    ws[o_dst + (long)bt*128 + t] = selu_f(s);
}

// ---------------- dueling head + taus passthrough ----------------
__global__ void k_head(float* ws, void* d_out, const void* taus_raw){
    __shared__ float row[128];
    __shared__ float advs[12];
    int bt = blockIdx.x, t = threadIdx.x;
    row[t] = ws[O_Z2 + (long)bt*128 + t];
    row[64 + t] = ws[O_Z2 + (long)bt*128 + 64 + t];
    __syncthreads();
    if (t < 11){
        const float* W = (t < 10) ? (ws + O_CAW + (long)t*128) : (ws + O_CVW);
        float s = (t < 10) ? ws[O_CAB + t] : ws[O_CVB];
        for (int i = 0; i < 128; i++) s += row[i]*W[i];
        advs[t] = s;
    }
    __syncthreads();
    if (t == 0){
        float m = 0.f;
        #pragma unroll
        for (int a = 0; a < 10; a++) m += advs[a];
        m *= 0.1f;
        float val = advs[10];
        int bf = ((const int*)ws)[0];
        if (bf){
            __hip_bfloat16* out = (__hip_bfloat16*)d_out;
            for (int a = 0; a < 10; a++) out[(long)bt*10 + a] = __float2bfloat16(val + advs[a] - m);
            ((unsigned short*)d_out)[16000 + bt] = ((const unsigned short*)taus_raw)[bt];
        } else {
            float* out = (float*)d_out;
            for (int a = 0; a < 10; a++) out[(long)bt*10 + a] = val + advs[a] - m;
            out[16000 + bt] = ((const float*)taus_raw)[bt];
        }
    }
}

// ---------------- launch ----------------
extern "C" void kernel_launch(void* const* d_in, const int* in_sizes, int n_in,
                              void* d_out, int out_size, void* d_ws, size_t ws_size,
                              hipStream_t stream){
    (void)in_sizes; (void)n_in; (void)out_size;
    float* ws = (float*)d_ws;
    const int* ei = (const int*)d_in[1];
    const int* et = (const int*)d_in[2];

    // zero atomic-target region (agg1, agg2, den1, den2, amax1, amax2)
    hipMemsetAsync(ws + O_AGG1, 0, (size_t)ZERO_CNT*4, stream);

    // mode detect + input conversion
    k_detect<<<1, 64, 0, stream>>>((const unsigned short*)d_in[3], (int*)d_ws);

    ConvArgs ca;
    static const long conv_o[38] = {
        O_X, -1, -1, O_TAU, O_W1, O_Q1, O_K1, O_B1, O_W2, O_Q2, O_K2, O_B2, O_CW, O_CB,
        O_F1W, O_F1B, O_F1SW, O_F1SB, O_F1EW, O_F1EB,
        O_F2W, O_F2B, O_F2SW, O_F2SB, O_F2EW, O_F2EB,
        O_AW, O_AB, O_ASW, O_ASB, O_AEW, O_AEB,
        O_VW, O_VB, O_VSW, O_VSB, O_VEW, O_VEB };
    static const int conv_n[38] = {
        40000, 0, 0, 1600, 4096, 2048, 2048, 128, 262144, 2048, 2048, 128, 8192, 128,
        16384, 128, 16384, 128, 16384, 128,
        16384, 128, 16384, 128, 16384, 128,
        1280, 10, 1280, 10, 1280, 10,
        128, 1, 128, 1, 128, 1 };
    for (int i = 0; i < 38; i++){ ca.src[i] = d_in[i]; ca.off[i] = conv_o[i]; ca.n[i] = conv_n[i]; }
    k_convert<<<dim3(1024, 38), 256, 0, stream>>>(ca, ws);

    k_fold<<<dim3(8, 4), 256, 0, stream>>>(ws);
    k_noisy<<<dim3(64, 8), 256, 0, stream>>>(ws);

    // ---- RGAT layer 1 ----
    k_alpha1<<<625, 256, 0, stream>>>(ei, et, ws);
    k_ex<<<625, 256, 0, stream>>>(ei, ws, O_AL1, O_AMAX1, O_DEN1);
    k_msg1<<<80000, 256, 0, stream>>>(ei, et, ws);
    k_h<<<10000, 256, 0, stream>>>(ws, O_AGG1, O_B1, O_H1);

    // ---- RGAT layer 2 ----
    bool use_table = ws_size >= (size_t)O_END_TABLE*4;
    if (use_table) k_xw2<<<1250, 256, 0, stream>>>(ws);
    k_alpha2<<<625, 256, 0, stream>>>(ei, et, ws);
    k_ex<<<625, 256, 0, stream>>>(ei, ws, O_AL2, O_AMAX2, O_DEN2);
    if (use_table) k_msg2<<<80000, 256, 0, stream>>>(ei, et, ws);
    else           k_msg2_direct<<<80000, 256, 0, stream>>>(ei, et, ws);
    k_h<<<10000, 256, 0, stream>>>(ws, O_AGG2, O_B2, O_H2);

    // ---- head ----
    k_pool<<<200, 128, 0, stream>>>(ws);
    k_cosz<<<1600, 128, 0, stream>>>(ws);
    k_ff<<<1600, 128, 0, stream>>>(ws, O_Z0, O_CF1W, O_CF1B, O_Z1);
    k_ff<<<1600, 128, 0, stream>>>(ws, O_Z1, O_CF2W, O_CF2B, O_Z2);
    k_head<<<1600, 64, 0, stream>>>(ws, d_out, d_in[3]);
}

// Round 2
// 489.478 us; speedup vs baseline: 1.3822x; 1.3822x over previous
//
#include <hip/hip_runtime.h>
#include <hip/hip_bf16.h>

// ---------------- problem constants ----------------
constexpr long NN = 20000;   // nodes
constexpr long NE = 160000;  // edges
constexpr long BB = 200;     // graphs
constexpr long TT = 8;       // taus
constexpr long GN = 100;     // nodes per graph

// ---------------- ws layout (f32 element offsets) ----------------
constexpr long O_FLAG = 0;                                      // int mode flag
constexpr long O_X    = 16;                 constexpr long N_X   = 40000;
constexpr long O_TAU  = O_X + N_X;          constexpr long N_TAU = 1600;
constexpr long O_W1   = O_TAU + N_TAU;      constexpr long N_W1  = 4096;
constexpr long O_Q1   = O_W1 + N_W1;        constexpr long N_Q   = 2048;
constexpr long O_K1   = O_Q1 + N_Q;
constexpr long O_B1   = O_K1 + N_Q;         constexpr long N_B   = 128;
constexpr long O_W2   = O_B1 + N_B;         constexpr long N_W2  = 262144;
constexpr long O_Q2   = O_W2 + N_W2;
constexpr long O_K2   = O_Q2 + N_Q;
constexpr long O_B2   = O_K2 + N_Q;
constexpr long O_CW   = O_B2 + N_B;         constexpr long N_CW  = 8192;
constexpr long O_CB   = O_CW + N_CW;
constexpr long O_F1W  = O_CB + N_B;         constexpr long N_FW  = 16384;
constexpr long O_F1B  = O_F1W + N_FW;
constexpr long O_F1SW = O_F1B + N_B;
constexpr long O_F1SB = O_F1SW + N_FW;
constexpr long O_F1EW = O_F1SB + N_B;
constexpr long O_F1EB = O_F1EW + N_FW;
constexpr long O_F2W  = O_F1EB + N_B;
constexpr long O_F2B  = O_F2W + N_FW;
constexpr long O_F2SW = O_F2B + N_B;
constexpr long O_F2SB = O_F2SW + N_FW;
constexpr long O_F2EW = O_F2SB + N_B;
constexpr long O_F2EB = O_F2EW + N_FW;
constexpr long O_AW   = O_F2EB + N_B;       constexpr long N_AW  = 1280;
constexpr long O_AB   = O_AW + N_AW;        constexpr long N_AB  = 16;  // 10 used
constexpr long O_ASW  = O_AB + N_AB;
constexpr long O_ASB  = O_ASW + N_AW;
constexpr long O_AEW  = O_ASB + N_AB;
constexpr long O_AEB  = O_AEW + N_AW;
constexpr long O_VW   = O_AEB + N_AB;       constexpr long N_VW  = 128;
constexpr long O_VB   = O_VW + N_VW;        constexpr long N_VB  = 16;  // 1 used
constexpr long O_VSW  = O_VB + N_VB;
constexpr long O_VSB  = O_VSW + N_VW;
constexpr long O_VEW  = O_VSB + N_VB;
constexpr long O_VEB  = O_VEW + N_VW;
// derived
constexpr long O_WQ1  = O_VEB + N_VB;       // [4][2][4] = 32
constexpr long O_WK1  = O_WQ1 + 32;
constexpr long O_WQ2  = O_WK1 + 32;         // [4][128][4] = 2048
constexpr long O_WK2  = O_WQ2 + 2048;
constexpr long O_CF1W = O_WK2 + 2048;       // combined noisy weights
constexpr long O_CF1B = O_CF1W + N_FW;
constexpr long O_CF2W = O_CF1B + N_B;
constexpr long O_CF2B = O_CF2W + N_FW;
constexpr long O_CAW  = O_CF2B + N_B;
constexpr long O_CAB  = O_CAW + N_AW;
constexpr long O_CVW  = O_CAB + N_AB;
constexpr long O_CVB  = O_CVW + N_VW;
constexpr long O_AL1  = O_CVB + N_VB;       // [E][4] logits -> exp
constexpr long O_AL2  = O_AL1 + NE*4;
constexpr long O_H1   = O_AL2 + NE*4;       // [N][128]
constexpr long O_H2   = O_H1 + NN*128;
constexpr long O_G    = O_H2 + NN*128;      // [200][128]
constexpr long O_Z0   = O_G + BB*128;       // [1600][128]
constexpr long O_Z1   = O_Z0 + BB*TT*128;
constexpr long O_Z2   = O_Z1 + BB*TT*128;
// zero-init region (contiguous)
constexpr long O_AGG1 = O_Z2 + BB*TT*128;   // [N][128]
constexpr long O_AGG2 = O_AGG1 + NN*128;
constexpr long O_DEN1 = O_AGG2 + NN*128;    // [N][4]
constexpr long O_DEN2 = O_DEN1 + NN*4;
constexpr long O_AMAX1= O_DEN2 + NN*4;      // [N][4] ordered-uint keys
constexpr long O_AMAX2= O_AMAX1 + NN*4;
constexpr long ZERO_CNT = (O_AMAX2 + NN*4) - O_AGG1;
// bf16 xw2 table [N][4][512] (viewed as u16)
constexpr long O_XW2  = O_AMAX2 + NN*4;
constexpr long O_END_TABLE = O_XW2 + (NN*4*512)/2;   // f32 slots for bf16 table
// MFMA-path extras (after table): h1 in bf16 (padded to 20096 rows), W2 transposed bf16
constexpr long MPAD   = 20096;
constexpr long O_H1B  = O_END_TABLE;                  // [20096][128] bf16
constexpr long O_W2BT = O_H1B + (MPAD*128)/2;         // [2048][128] bf16  Bt[n][k]
constexpr long O_END2 = O_W2BT + (2048L*128)/2;

#define DEVFN __device__ __forceinline__

typedef __attribute__((ext_vector_type(8))) short bf16x8;
typedef __attribute__((ext_vector_type(4))) float f32x4;

DEVFN float selu_f(float x){ return 1.0507009873554805f * (x > 0.f ? x : 1.6732632423543772f * expm1f(x)); }
DEVFN float lrelu_f(float x){ return x >= 0.f ? x : 0.2f * x; }
DEVFN unsigned fkey(float x){ unsigned b = __float_as_uint(x); return (b & 0x80000000u) ? ~b : (b | 0x80000000u); }
DEVFN float fkey_inv(unsigned k){ unsigned b = (k & 0x80000000u) ? (k ^ 0x80000000u) : ~k; return __uint_as_float(b); }

// ---------------- mode detection ----------------
__global__ void k_detect(const unsigned short* taus_u16, int* flag){
    if (threadIdx.x == 0){
        int bf = 1;
        for (int i = 0; i < 128; i++){
            if (taus_u16[i] > 0x3F80u){ bf = 0; break; }   // bf16 uniform[0,1] never exceeds 1.0
        }
        *flag = bf;
    }
}

// ---------------- convert all float inputs to f32 in ws ----------------
struct ConvArgs { const void* src[38]; long off[38]; int n[38]; };

__global__ void k_convert(ConvArgs a, float* ws){
    int arr = blockIdx.y;
    long off = a.off[arr];
    if (off < 0) return;
    const void* s = a.src[arr];
    int n = a.n[arr];
    int bf = ((const int*)ws)[0];
    for (int i = blockIdx.x*blockDim.x + threadIdx.x; i < n; i += gridDim.x*blockDim.x){
        float v;
        if (bf){ unsigned short u = ((const unsigned short*)s)[i]; v = __uint_as_float(((unsigned)u) << 16); }
        else   { v = ((const float*)s)[i]; }
        ws[off + i] = v;
    }
}

// ---------------- fold W@q / W@k ----------------
__global__ void k_fold(float* ws){
    int task = blockIdx.y;
    int idx = blockIdx.x*blockDim.x + threadIdx.x;
    if (task < 2){                       // layer1: [r*2+i][h], 32 outputs, K=512
        if (idx >= 32) return;
        int h = idx & 3, ri = idx >> 2;
        const float* W = ws + O_W1 + (long)ri*512;
        const float* Q = ws + (task == 0 ? O_Q1 : O_K1);
        float s = 0.f;
        for (int o = 0; o < 512; o++) s += W[o] * Q[o*4 + h];
        ws[(task == 0 ? O_WQ1 : O_WK1) + idx] = s;
    } else {                             // layer2: [r*128+i][h], 2048 outputs, K=512
        if (idx >= 2048) return;
        int h = idx & 3, ri = idx >> 2;
        const float* W = ws + O_W2 + (long)ri*512;
        const float* Q = ws + (task == 2 ? O_Q2 : O_K2);
        float s = 0.f;
        for (int o = 0; o < 512; o++) s += W[o] * Q[o*4 + h];
        ws[(task == 2 ? O_WQ2 : O_WK2) + idx] = s;
    }
}

// ---------------- combine noisy weights: w + sw*ew, b + sb*eb ----------------
__global__ void k_noisy(float* ws){
    const long tw[8] = {O_F1W,O_F2W,O_AW,O_VW, O_F1B,O_F2B,O_AB,O_VB};
    const long ts[8] = {O_F1SW,O_F2SW,O_ASW,O_VSW, O_F1SB,O_F2SB,O_ASB,O_VSB};
    const long te[8] = {O_F1EW,O_F2EW,O_AEW,O_VEW, O_F1EB,O_F2EB,O_AEB,O_VEB};
    const long td[8] = {O_CF1W,O_CF2W,O_CAW,O_CVW, O_CF1B,O_CF2B,O_CAB,O_CVB};
    const int  tn[8] = {16384,16384,1280,128, 128,128,10,1};
    int t = blockIdx.y;
    for (int i = blockIdx.x*blockDim.x + threadIdx.x; i < tn[t]; i += gridDim.x*blockDim.x)
        ws[td[t] + i] = ws[tw[t] + i] + ws[ts[t] + i]*ws[te[t] + i];
}

// ---------------- W2 -> Bt[n][k] bf16 (for MFMA B operand) ----------------
__global__ void k_w2b(float* ws){
    int idx = blockIdx.x*blockDim.x + threadIdx.x;   // 0..262143
    int n = idx & 2047, k = idx >> 11;
    float v = ws[O_W2 + (long)(n >> 9)*65536 + (long)k*512 + (n & 511)];
    ((__hip_bfloat16*)(ws + O_W2BT))[(long)n*128 + k] = __float2bfloat16(v);
}

// ---------------- zero the pad rows of H1B ----------------
__global__ void k_zpad(float* ws){
    int i = blockIdx.x*blockDim.x + threadIdx.x;     // 6144 f32 slots = 12288 bf16
    if (i < 6144) ws[O_H1B + (20000L*128)/2 + i] = 0.f;
}

// ---------------- layer 1: attention logits + segment max ----------------
__global__ void k_alpha1(const int* ei, const int* et, float* ws){
    long e = (long)blockIdx.x*blockDim.x + threadIdx.x;
    if (e >= NE) return;
    int src = ei[e], dst = ei[NE + e], rt = et[e];
    float xs0 = ws[O_X + (long)src*2], xs1 = ws[O_X + (long)src*2 + 1];
    float xd0 = ws[O_X + (long)dst*2], xd1 = ws[O_X + (long)dst*2 + 1];
    const float* Wq = ws + O_WQ1 + rt*8;   // [i*4+h]
    const float* Wk = ws + O_WK1 + rt*8;
    unsigned* am = (unsigned*)(ws + O_AMAX1);
    #pragma unroll
    for (int h = 0; h < 4; h++){
        float a = xd0*Wq[h] + xd1*Wq[4+h] + xs0*Wk[h] + xs1*Wk[4+h];
        a = lrelu_f(a);
        ws[O_AL1 + e*4 + h] = a;
        atomicMax(&am[(long)dst*4 + h], fkey(a));
    }
}

// ---------------- shared: exp(alpha - amax) + segment sum ----------------
__global__ void k_ex(const int* ei, float* ws, long o_al, long o_amax, long o_den){
    long e = (long)blockIdx.x*blockDim.x + threadIdx.x;
    if (e >= NE) return;
    int dst = ei[NE + e];
    const unsigned* am = (const unsigned*)(ws + o_amax);
    #pragma unroll
    for (int h = 0; h < 4; h++){
        float mx = fkey_inv(am[(long)dst*4 + h]);
        float ex = expf(ws[o_al + e*4 + h] - mx);
        ws[o_al + e*4 + h] = ex;
        atomicAdd(&ws[o_den + (long)dst*4 + h], ex);
    }
}

// ---------------- layer 1 messages: head-combined 128-float atomic add ----------------
__global__ void k_msg1(const int* ei, const int* et, float* ws){
    int le = threadIdx.x >> 7, d = threadIdx.x & 127;
    long e = (long)blockIdx.x*2 + le;
    if (e >= NE) return;
    int src = ei[e], dst = ei[NE + e], rt = et[e];
    float xs0 = ws[O_X + (long)src*2], xs1 = ws[O_X + (long)src*2 + 1];
    float v = 0.f;
    #pragma unroll
    for (int h = 0; h < 4; h++){
        float a = ws[O_AL1 + e*4 + h] / ws[O_DEN1 + (long)dst*4 + h];
        const float* W = ws + O_W1 + (long)(rt*2)*512 + h*128 + d;   // i=0 row; +512 -> i=1
        v += a * (xs0*W[0] + xs1*W[512]);
    }
    atomicAdd(&ws[O_AGG1 + (long)dst*128 + d], 0.25f * v);
}

// ---------------- h = selu(agg + b); optionally mirror to bf16 ----------------
__global__ void k_h(float* ws, long o_agg, long o_b, long o_dst, long o_bf){
    long i = (long)blockIdx.x*blockDim.x + threadIdx.x;
    if (i >= NN*128) return;
    int d = (int)(i & 127);
    float v = selu_f(ws[o_agg + i] + ws[o_b + d]);
    ws[o_dst + i] = v;
    if (o_bf >= 0) ((__hip_bfloat16*)(ws + o_bf))[i] = __float2bfloat16(v);
}

// ---------------- xw2 = h1 @ W2 via MFMA (bf16 in, f32 acc, bf16 table out) ----------------
// A: H1B [20096][128] bf16 row-major; B: W2BT [2048][128] bf16 (Bt[n][k]).
// Block 256 thr = 4 waves; tile 128(M)x128(N), K=128 single LDS stage.
// LDS XOR-swizzle: 16B granule ^= ((row&7)<<4) on both write and read (T2).
__global__ void k_xw2_mfma(float* ws){
    __shared__ __align__(16) unsigned short Ash[128*128];   // 32 KB
    __shared__ __align__(16) unsigned short Bsh[128*128];   // 32 KB
    const unsigned short* h1b  = (const unsigned short*)(ws + O_H1B);
    const unsigned short* w2bt = (const unsigned short*)(ws + O_W2BT);
    long bm = (long)blockIdx.x * 128;
    long bn = (long)blockIdx.y * 128;
    int tid = threadIdx.x;
    char* Ac = (char*)Ash; char* Bc = (char*)Bsh;
    #pragma unroll
    for (int i = 0; i < 8; i++){
        int c = tid + i*256;                 // 0..2047 chunks of 16B
        int row = c >> 4, kb = (c & 15) * 16;
        int off = row*256 + (kb ^ ((row & 7) << 4));
        *(bf16x8*)(Ac + off) = *(const bf16x8*)&h1b [(bm + row)*128 + (c & 15)*8];
        *(bf16x8*)(Bc + off) = *(const bf16x8*)&w2bt[(bn + row)*128 + (c & 15)*8];
    }
    __syncthreads();
    int w = tid >> 6, lane = tid & 63;
    int wm = (w >> 1) * 64, wn = (w & 1) * 64;
    int r16 = lane & 15, kq = lane >> 4;
    f32x4 acc[4][4] = {};
    #pragma unroll
    for (int ks = 0; ks < 4; ks++){
        int kbyte = ks*64 + kq*16;
        bf16x8 a[4], b[4];
        #pragma unroll
        for (int m = 0; m < 4; m++){
            int row = wm + m*16 + r16;
            a[m] = *(const bf16x8*)(Ac + row*256 + (kbyte ^ ((row & 7) << 4)));
        }
        #pragma unroll
        for (int n = 0; n < 4; n++){
            int row = wn + n*16 + r16;
            b[n] = *(const bf16x8*)(Bc + row*256 + (kbyte ^ ((row & 7) << 4)));
        }
        #pragma unroll
        for (int m = 0; m < 4; m++)
            #pragma unroll
            for (int n = 0; n < 4; n++)
                acc[m][n] = __builtin_amdgcn_mfma_f32_16x16x32_bf16(a[m], b[n], acc[m][n], 0, 0, 0);
    }
    // C/D layout: col = lane&15, row = (lane>>4)*4 + reg
    __hip_bfloat16* xb = (__hip_bfloat16*)(ws + O_XW2);
    #pragma unroll
    for (int m = 0; m < 4; m++){
        long gr0 = bm + wm + m*16 + kq*4;
        #pragma unroll
        for (int j = 0; j < 4; j++){
            long gr = gr0 + j;
            if (gr < NN){
                #pragma unroll
                for (int n = 0; n < 4; n++){
                    long gc = bn + wn + n*16 + r16;
                    xb[gr*2048 + gc] = __float2bfloat16(acc[m][n][j]);
                }
            }
        }
    }
}

// ---------------- xw2 fallback (VALU) ----------------
__global__ void k_xw2(float* ws){
    __shared__ float hrow[16][128];
    long nb = (long)blockIdx.x * 16;
    int t = threadIdx.x;
    for (int k = 0; k < 8; k++){
        int idx = k*256 + t;
        hrow[idx >> 7][idx & 127] = ws[O_H1 + nb*128 + idx];
    }
    __syncthreads();
    __hip_bfloat16* xb = (__hip_bfloat16*)(ws + O_XW2);
    for (int k = 0; k < 8; k++){
        int o = k*256 + t;                  // 0..2047
        int r = o >> 9, oi = o & 511;
        const float* W = ws + O_W2 + (long)r*65536 + oi;   // stride 512 over i
        float acc[16];
        #pragma unroll
        for (int j = 0; j < 16; j++) acc[j] = 0.f;
        for (int i = 0; i < 128; i++){
            float w = W[(long)i*512];
            #pragma unroll
            for (int j = 0; j < 16; j++) acc[j] += hrow[j][i]*w;
        }
        for (int j = 0; j < 16; j++) xb[(nb + j)*2048 + o] = __float2bfloat16(acc[j]);
    }
}

// ---------------- layer 2 logits via folded Wq2/Wk2 ----------------
__global__ void k_alpha2(const int* ei, const int* et, float* ws){
    long e = (long)blockIdx.x*blockDim.x + threadIdx.x;
    if (e >= NE) return;
    int src = ei[e], dst = ei[NE + e], rt = et[e];
    const float4* hs4 = (const float4*)(ws + O_H1 + (long)src*128);
    const float4* hd4 = (const float4*)(ws + O_H1 + (long)dst*128);
    const float* Wq = ws + O_WQ2 + (long)rt*512;   // [i*4+h]
    const float* Wk = ws + O_WK2 + (long)rt*512;
    float a[4] = {0.f,0.f,0.f,0.f};
    for (int i0 = 0; i0 < 32; i0++){
        float4 s4 = hs4[i0], d4 = hd4[i0];
        const float* wq = Wq + i0*16;
        const float* wk = Wk + i0*16;
        #pragma unroll
        for (int h = 0; h < 4; h++){
            a[h] += d4.x*wq[h] + d4.y*wq[4+h] + d4.z*wq[8+h] + d4.w*wq[12+h]
                  + s4.x*wk[h] + s4.y*wk[4+h] + s4.z*wk[8+h] + s4.w*wk[12+h];
        }
    }
    unsigned* am = (unsigned*)(ws + O_AMAX2);
    #pragma unroll
    for (int h = 0; h < 4; h++){
        float v = lrelu_f(a[h]);
        ws[O_AL2 + e*4 + h] = v;
        atomicMax(&am[(long)dst*4 + h], fkey(v));
    }
}

// ---------------- layer 2 messages via bf16 table ----------------
__global__ void k_msg2(const int* ei, const int* et, float* ws){
    int le = threadIdx.x >> 7, d = threadIdx.x & 127;
    long e = (long)blockIdx.x*2 + le;
    if (e >= NE) return;
    int src = ei[e], dst = ei[NE + e], rt = et[e];
    const __hip_bfloat16* xr = (const __hip_bfloat16*)(ws + O_XW2) + ((long)src*4 + rt)*512;
    float v = 0.f;
    #pragma unroll
    for (int h = 0; h < 4; h++){
        float a = ws[O_AL2 + e*4 + h] / ws[O_DEN2 + (long)dst*4 + h];
        v += a * __bfloat162float(xr[h*128 + d]);
    }
    atomicAdd(&ws[O_AGG2 + (long)dst*128 + d], 0.25f * v);
}

// ---------------- layer 2 messages, no-table fallback ----------------
__global__ void k_msg2_direct(const int* ei, const int* et, float* ws){
    __shared__ float hsrow[2][128];
    __shared__ float ash[2][4];
    int le = threadIdx.x >> 7, d = threadIdx.x & 127;
    long e = (long)blockIdx.x*2 + le;
    int src = 0, dst = 0, rt = 0;
    bool ok = (e < NE);
    if (ok){
        src = ei[e]; dst = ei[NE + e]; rt = et[e];
        hsrow[le][d] = ws[O_H1 + (long)src*128 + d];
        if (d < 4) ash[le][d] = ws[O_AL2 + e*4 + d] / ws[O_DEN2 + (long)dst*4 + d];
    }
    __syncthreads();
    if (!ok) return;
    float a0 = ash[le][0]*0.25f, a1 = ash[le][1]*0.25f, a2 = ash[le][2]*0.25f, a3 = ash[le][3]*0.25f;
    const float* W = ws + O_W2 + (long)rt*65536 + d;
    float v = 0.f;
    for (int i = 0; i < 128; i++){
        const float* Wi = W + (long)i*512;
        v += hsrow[le][i] * (a0*Wi[0] + a1*Wi[128] + a2*Wi[256] + a3*Wi[384]);
    }
    atomicAdd(&ws[O_AGG2 + (long)dst*128 + d], v);
}

// ---------------- global add pool ----------------
__global__ void k_pool(float* ws){
    int b = blockIdx.x, d = threadIdx.x;
    float s = 0.f;
    for (int j = 0; j < GN; j++) s += ws[O_H2 + ((long)b*GN + j)*128 + d];
    ws[O_G + (long)b*128 + d] = s;
}

// ---------------- cosine embedding + z = g * relu(cos @ cw^T + cb) ----------------
__global__ void k_cosz(float* ws){
    __shared__ float cs[64];
    int bt = blockIdx.x, t = threadIdx.x;
    if (t < 64){
        float tau = ws[O_TAU + bt];
        cs[t] = cosf(tau * (3.14159265358979323846f * (float)(t + 1)));
    }
    __syncthreads();
    int b = bt >> 3;   // T = 8
    const float* cw = ws + O_CW + (long)t*64;
    float s = ws[O_CB + t];
    for (int c = 0; c < 64; c++) s += cs[c]*cw[c];
    s = fmaxf(s, 0.f);
    ws[O_Z0 + (long)bt*128 + t] = ws[O_G + (long)b*128 + t] * s;
}

// ---------------- noisy FF layer: dst = selu(src @ W^T + B) ----------------
__global__ void k_ff(float* ws, long o_src, long o_w, long o_b, long o_dst){
    __shared__ float row[128];
    int bt = blockIdx.x, t = threadIdx.x;
    row[t] = ws[o_src + (long)bt*128 + t];
    __syncthreads();
    const float* W = ws + o_w + (long)t*128;
    float s = ws[o_b + t];
    for (int i = 0; i < 128; i++) s += row[i]*W[i];
    ws[o_dst + (long)bt*128 + t] = selu_f(s);
}

// ---------------- dueling head + taus passthrough ----------------
__global__ void k_head(float* ws, void* d_out, const void* taus_raw){
    __shared__ float row[128];
    __shared__ float advs[12];
    int bt = blockIdx.x, t = threadIdx.x;
    row[t] = ws[O_Z2 + (long)bt*128 + t];
    row[64 + t] = ws[O_Z2 + (long)bt*128 + 64 + t];
    __syncthreads();
    if (t < 11){
        const float* W = (t < 10) ? (ws + O_CAW + (long)t*128) : (ws + O_CVW);
        float s = (t < 10) ? ws[O_CAB + t] : ws[O_CVB];
        for (int i = 0; i < 128; i++) s += row[i]*W[i];
        advs[t] = s;
    }
    __syncthreads();
    if (t == 0){
        float m = 0.f;
        #pragma unroll
        for (int a = 0; a < 10; a++) m += advs[a];
        m *= 0.1f;
        float val = advs[10];
        int bf = ((const int*)ws)[0];
        if (bf){
            __hip_bfloat16* out = (__hip_bfloat16*)d_out;
            for (int a = 0; a < 10; a++) out[(long)bt*10 + a] = __float2bfloat16(val + advs[a] - m);
            ((unsigned short*)d_out)[16000 + bt] = ((const unsigned short*)taus_raw)[bt];
        } else {
            float* out = (float*)d_out;
            for (int a = 0; a < 10; a++) out[(long)bt*10 + a] = val + advs[a] - m;
            out[16000 + bt] = ((const float*)taus_raw)[bt];
        }
    }
}

// ---------------- launch ----------------
extern "C" void kernel_launch(void* const* d_in, const int* in_sizes, int n_in,
                              void* d_out, int out_size, void* d_ws, size_t ws_size,
                              hipStream_t stream){
    (void)in_sizes; (void)n_in; (void)out_size;
    float* ws = (float*)d_ws;
    const int* ei = (const int*)d_in[1];
    const int* et = (const int*)d_in[2];

    bool use_mfma  = ws_size >= (size_t)O_END2*4;
    bool use_table = ws_size >= (size_t)O_END_TABLE*4;

    // zero atomic-target region (agg1, agg2, den1, den2, amax1, amax2)
    hipMemsetAsync(ws + O_AGG1, 0, (size_t)ZERO_CNT*4, stream);

    // mode detect + input conversion
    k_detect<<<1, 64, 0, stream>>>((const unsigned short*)d_in[3], (int*)d_ws);

    ConvArgs ca;
    static const long conv_o[38] = {
        O_X, -1, -1, O_TAU, O_W1, O_Q1, O_K1, O_B1, O_W2, O_Q2, O_K2, O_B2, O_CW, O_CB,
        O_F1W, O_F1B, O_F1SW, O_F1SB, O_F1EW, O_F1EB,
        O_F2W, O_F2B, O_F2SW, O_F2SB, O_F2EW, O_F2EB,
        O_AW, O_AB, O_ASW, O_ASB, O_AEW, O_AEB,
        O_VW, O_VB, O_VSW, O_VSB, O_VEW, O_VEB };
    static const int conv_n[38] = {
        40000, 0, 0, 1600, 4096, 2048, 2048, 128, 262144, 2048, 2048, 128, 8192, 128,
        16384, 128, 16384, 128, 16384, 128,
        16384, 128, 16384, 128, 16384, 128,
        1280, 10, 1280, 10, 1280, 10,
        128, 1, 128, 1, 128, 1 };
    for (int i = 0; i < 38; i++){ ca.src[i] = d_in[i]; ca.off[i] = conv_o[i]; ca.n[i] = conv_n[i]; }
    k_convert<<<dim3(1024, 38), 256, 0, stream>>>(ca, ws);

    k_fold<<<dim3(8, 4), 256, 0, stream>>>(ws);
    k_noisy<<<dim3(64, 8), 256, 0, stream>>>(ws);
    if (use_mfma){
        k_w2b<<<1024, 256, 0, stream>>>(ws);
        k_zpad<<<24, 256, 0, stream>>>(ws);
    }

    // ---- RGAT layer 1 ----
    k_alpha1<<<625, 256, 0, stream>>>(ei, et, ws);
    k_ex<<<625, 256, 0, stream>>>(ei, ws, O_AL1, O_AMAX1, O_DEN1);
    k_msg1<<<80000, 256, 0, stream>>>(ei, et, ws);
    k_h<<<10000, 256, 0, stream>>>(ws, O_AGG1, O_B1, O_H1, use_mfma ? O_H1B : -1);

    // ---- RGAT layer 2 ----
    if (use_mfma)       k_xw2_mfma<<<dim3(157, 16), 256, 0, stream>>>(ws);
    else if (use_table) k_xw2<<<1250, 256, 0, stream>>>(ws);
    k_alpha2<<<625, 256, 0, stream>>>(ei, et, ws);
    k_ex<<<625, 256, 0, stream>>>(ei, ws, O_AL2, O_AMAX2, O_DEN2);
    if (use_table) k_msg2<<<80000, 256, 0, stream>>>(ei, et, ws);
    else           k_msg2_direct<<<80000, 256, 0, stream>>>(ei, et, ws);
    k_h<<<10000, 256, 0, stream>>>(ws, O_AGG2, O_B2, O_H2, -1);

    // ---- head ----
    k_pool<<<200, 128, 0, stream>>>(ws);
    k_cosz<<<1600, 128, 0, stream>>>(ws);
    k_ff<<<1600, 128, 0, stream>>>(ws, O_Z0, O_CF1W, O_CF1B, O_Z1);
    k_ff<<<1600, 128, 0, stream>>>(ws, O_Z1, O_CF2W, O_CF2B, O_Z2);
    k_head<<<1600, 64, 0, stream>>>(ws, d_out, d_in[3]);
}

// Round 3
// 433.930 us; speedup vs baseline: 1.5592x; 1.1280x over previous
//
#include <hip/hip_runtime.h>
#include <hip/hip_bf16.h>

// ---------------- problem constants ----------------
constexpr long NN = 20000;   // nodes
constexpr long NE = 160000;  // edges
constexpr long BB = 200;     // graphs
constexpr long TT = 8;       // taus
constexpr long GN = 100;     // nodes per graph

// ---------------- ws layout (f32 element offsets) ----------------
constexpr long O_FLAG = 0;                                      // int mode flag
constexpr long O_X    = 16;                 constexpr long N_X   = 40000;
constexpr long O_TAU  = O_X + N_X;          constexpr long N_TAU = 1600;
constexpr long O_W1   = O_TAU + N_TAU;      constexpr long N_W1  = 4096;
constexpr long O_Q1   = O_W1 + N_W1;        constexpr long N_Q   = 2048;
constexpr long O_K1   = O_Q1 + N_Q;
constexpr long O_B1   = O_K1 + N_Q;         constexpr long N_B   = 128;
constexpr long O_W2   = O_B1 + N_B;         constexpr long N_W2  = 262144;
constexpr long O_Q2   = O_W2 + N_W2;
constexpr long O_K2   = O_Q2 + N_Q;
constexpr long O_B2   = O_K2 + N_Q;
constexpr long O_CW   = O_B2 + N_B;         constexpr long N_CW  = 8192;
constexpr long O_CB   = O_CW + N_CW;
constexpr long O_F1W  = O_CB + N_B;         constexpr long N_FW  = 16384;
constexpr long O_F1B  = O_F1W + N_FW;
constexpr long O_F1SW = O_F1B + N_B;
constexpr long O_F1SB = O_F1SW + N_FW;
constexpr long O_F1EW = O_F1SB + N_B;
constexpr long O_F1EB = O_F1EW + N_FW;
constexpr long O_F2W  = O_F1EB + N_B;
constexpr long O_F2B  = O_F2W + N_FW;
constexpr long O_F2SW = O_F2B + N_B;
constexpr long O_F2SB = O_F2SW + N_FW;
constexpr long O_F2EW = O_F2SB + N_B;
constexpr long O_F2EB = O_F2EW + N_FW;
constexpr long O_AW   = O_F2EB + N_B;       constexpr long N_AW  = 1280;
constexpr long O_AB   = O_AW + N_AW;        constexpr long N_AB  = 16;  // 10 used
constexpr long O_ASW  = O_AB + N_AB;
constexpr long O_ASB  = O_ASW + N_AW;
constexpr long O_AEW  = O_ASB + N_AB;
constexpr long O_AEB  = O_AEW + N_AW;
constexpr long O_VW   = O_AEB + N_AB;       constexpr long N_VW  = 128;
constexpr long O_VB   = O_VW + N_VW;        constexpr long N_VB  = 16;  // 1 used
constexpr long O_VSW  = O_VB + N_VB;
constexpr long O_VSB  = O_VSW + N_VW;
constexpr long O_VEW  = O_VSB + N_VB;
constexpr long O_VEB  = O_VEW + N_VW;
// derived
constexpr long O_WQ1  = O_VEB + N_VB;       // [4][2][4] = 32
constexpr long O_WK1  = O_WQ1 + 32;
constexpr long O_WQ2  = O_WK1 + 32;         // [4][128][4] = 2048
constexpr long O_WK2  = O_WQ2 + 2048;
constexpr long O_CF1W = O_WK2 + 2048;       // combined noisy weights
constexpr long O_CF1B = O_CF1W + N_FW;
constexpr long O_CF2W = O_CF1B + N_B;
constexpr long O_CF2B = O_CF2W + N_FW;
constexpr long O_CAW  = O_CF2B + N_B;
constexpr long O_CAB  = O_CAW + N_AW;
constexpr long O_CVW  = O_CAB + N_AB;
constexpr long O_CVB  = O_CVW + N_VW;
constexpr long O_AL1  = O_CVB + N_VB;       // [E][4] logits -> exp
constexpr long O_AL2  = O_AL1 + NE*4;
constexpr long O_H1   = O_AL2 + NE*4;       // [N][128]
constexpr long O_H2   = O_H1 + NN*128;
constexpr long O_G    = O_H2 + NN*128;      // [200][128]
constexpr long O_Z0   = O_G + BB*128;       // [1600][128]
constexpr long O_Z1   = O_Z0 + BB*TT*128;
constexpr long O_Z2   = O_Z1 + BB*TT*128;
// zero-init region (contiguous)
constexpr long O_AGG1 = O_Z2 + BB*TT*128;   // [N][128]
constexpr long O_AGG2 = O_AGG1 + NN*128;
constexpr long O_DEN1 = O_AGG2 + NN*128;    // [N][4]
constexpr long O_DEN2 = O_DEN1 + NN*4;
constexpr long O_AMAX1= O_DEN2 + NN*4;      // [N][4] ordered-uint keys
constexpr long O_AMAX2= O_AMAX1 + NN*4;
constexpr long ZERO_CNT = (O_AMAX2 + NN*4) - O_AGG1;
// bf16 xw2 table [N][4][512] (viewed as u16)
constexpr long O_XW2  = O_AMAX2 + NN*4;
constexpr long O_END_TABLE = O_XW2 + (NN*4*512)/2;   // f32 slots for bf16 table
// MFMA-path extras (after table): h1 in bf16 (padded to 20096 rows), W2 transposed bf16
constexpr long MPAD   = 20096;
constexpr long O_H1B  = O_END_TABLE;                  // [20096][128] bf16
constexpr long O_W2BT = O_H1B + (MPAD*128)/2;         // [2048][128] bf16  Bt[n][k]
constexpr long O_END2 = O_W2BT + (2048L*128)/2;
// AQ/AK tables for layer-2 attention logits: [N][16] f32, idx = r*4+h
constexpr long O_AQ   = O_END2;
constexpr long O_AK   = O_AQ + NN*16;
constexpr long O_END3 = O_AK + NN*16;

#define DEVFN __device__ __forceinline__

typedef __attribute__((ext_vector_type(8))) short bf16x8;
typedef __attribute__((ext_vector_type(4))) float f32x4;

DEVFN float selu_f(float x){ return 1.0507009873554805f * (x > 0.f ? x : 1.6732632423543772f * expm1f(x)); }
DEVFN float lrelu_f(float x){ return x >= 0.f ? x : 0.2f * x; }
DEVFN unsigned fkey(float x){ unsigned b = __float_as_uint(x); return (b & 0x80000000u) ? ~b : (b | 0x80000000u); }
DEVFN float fkey_inv(unsigned k){ unsigned b = (k & 0x80000000u) ? (k ^ 0x80000000u) : ~k; return __uint_as_float(b); }

// ---------------- mode detection ----------------
__global__ void k_detect(const unsigned short* taus_u16, int* flag){
    if (threadIdx.x == 0){
        int bf = 1;
        for (int i = 0; i < 128; i++){
            if (taus_u16[i] > 0x3F80u){ bf = 0; break; }   // bf16 uniform[0,1] never exceeds 1.0
        }
        *flag = bf;
    }
}

// ---------------- convert all float inputs to f32 in ws ----------------
struct ConvArgs { const void* src[38]; long off[38]; int n[38]; };

__global__ void k_convert(ConvArgs a, float* ws){
    int arr = blockIdx.y;
    long off = a.off[arr];
    if (off < 0) return;
    const void* s = a.src[arr];
    int n = a.n[arr];
    int bf = ((const int*)ws)[0];
    for (int i = blockIdx.x*blockDim.x + threadIdx.x; i < n; i += gridDim.x*blockDim.x){
        float v;
        if (bf){ unsigned short u = ((const unsigned short*)s)[i]; v = __uint_as_float(((unsigned)u) << 16); }
        else   { v = ((const float*)s)[i]; }
        ws[off + i] = v;
    }
}

// ---------------- fold W@q / W@k ----------------
__global__ void k_fold(float* ws){
    int task = blockIdx.y;
    int idx = blockIdx.x*blockDim.x + threadIdx.x;
    if (task < 2){                       // layer1: [r*2+i][h], 32 outputs, K=512
        if (idx >= 32) return;
        int h = idx & 3, ri = idx >> 2;
        const float* W = ws + O_W1 + (long)ri*512;
        const float* Q = ws + (task == 0 ? O_Q1 : O_K1);
        float s = 0.f;
        for (int o = 0; o < 512; o++) s += W[o] * Q[o*4 + h];
        ws[(task == 0 ? O_WQ1 : O_WK1) + idx] = s;
    } else {                             // layer2: [r*128+i][h], 2048 outputs, K=512
        if (idx >= 2048) return;
        int h = idx & 3, ri = idx >> 2;
        const float* W = ws + O_W2 + (long)ri*512;
        const float* Q = ws + (task == 2 ? O_Q2 : O_K2);
        float s = 0.f;
        for (int o = 0; o < 512; o++) s += W[o] * Q[o*4 + h];
        ws[(task == 2 ? O_WQ2 : O_WK2) + idx] = s;
    }
}

// ---------------- combine noisy weights: w + sw*ew, b + sb*eb ----------------
__global__ void k_noisy(float* ws){
    const long tw[8] = {O_F1W,O_F2W,O_AW,O_VW, O_F1B,O_F2B,O_AB,O_VB};
    const long ts[8] = {O_F1SW,O_F2SW,O_ASW,O_VSW, O_F1SB,O_F2SB,O_ASB,O_VSB};
    const long te[8] = {O_F1EW,O_F2EW,O_AEW,O_VEW, O_F1EB,O_F2EB,O_AEB,O_VEB};
    const long td[8] = {O_CF1W,O_CF2W,O_CAW,O_CVW, O_CF1B,O_CF2B,O_CAB,O_CVB};
    const int  tn[8] = {16384,16384,1280,128, 128,128,10,1};
    int t = blockIdx.y;
    for (int i = blockIdx.x*blockDim.x + threadIdx.x; i < tn[t]; i += gridDim.x*blockDim.x)
        ws[td[t] + i] = ws[tw[t] + i] + ws[ts[t] + i]*ws[te[t] + i];
}

// ---------------- W2 -> Bt[n][k] bf16 (for MFMA B operand) ----------------
__global__ void k_w2b(float* ws){
    int idx = blockIdx.x*blockDim.x + threadIdx.x;   // 0..262143
    int n = idx & 2047, k = idx >> 11;
    float v = ws[O_W2 + (long)(n >> 9)*65536 + (long)k*512 + (n & 511)];
    ((__hip_bfloat16*)(ws + O_W2BT))[(long)n*128 + k] = __float2bfloat16(v);
}

// ---------------- zero the pad rows of H1B ----------------
__global__ void k_zpad(float* ws){
    int i = blockIdx.x*blockDim.x + threadIdx.x;     // 6144 f32 slots = 12288 bf16
    if (i < 6144) ws[O_H1B + (20000L*128)/2 + i] = 0.f;
}

// ---------------- layer 1: attention logits + segment max ----------------
__global__ void k_alpha1(const int* ei, const int* et, float* ws){
    long e = (long)blockIdx.x*blockDim.x + threadIdx.x;
    if (e >= NE) return;
    int src = ei[e], dst = ei[NE + e], rt = et[e];
    float xs0 = ws[O_X + (long)src*2], xs1 = ws[O_X + (long)src*2 + 1];
    float xd0 = ws[O_X + (long)dst*2], xd1 = ws[O_X + (long)dst*2 + 1];
    const float* Wq = ws + O_WQ1 + rt*8;   // [i*4+h]
    const float* Wk = ws + O_WK1 + rt*8;
    unsigned* am = (unsigned*)(ws + O_AMAX1);
    #pragma unroll
    for (int h = 0; h < 4; h++){
        float a = xd0*Wq[h] + xd1*Wq[4+h] + xs0*Wk[h] + xs1*Wk[4+h];
        a = lrelu_f(a);
        ws[O_AL1 + e*4 + h] = a;
        atomicMax(&am[(long)dst*4 + h], fkey(a));
    }
}

// ---------------- shared: exp(alpha - amax) + segment sum ----------------
__global__ void k_ex(const int* ei, float* ws, long o_al, long o_amax, long o_den){
    long e = (long)blockIdx.x*blockDim.x + threadIdx.x;
    if (e >= NE) return;
    int dst = ei[NE + e];
    const unsigned* am = (const unsigned*)(ws + o_amax);
    #pragma unroll
    for (int h = 0; h < 4; h++){
        float mx = fkey_inv(am[(long)dst*4 + h]);
        float ex = expf(ws[o_al + e*4 + h] - mx);
        ws[o_al + e*4 + h] = ex;
        atomicAdd(&ws[o_den + (long)dst*4 + h], ex);
    }
}

// ---------------- layer 1 messages: head-combined 128-float atomic add ----------------
__global__ void k_msg1(const int* ei, const int* et, float* ws){
    int le = threadIdx.x >> 7, d = threadIdx.x & 127;
    long e = (long)blockIdx.x*2 + le;
    if (e >= NE) return;
    int src = ei[e], dst = ei[NE + e], rt = et[e];
    float xs0 = ws[O_X + (long)src*2], xs1 = ws[O_X + (long)src*2 + 1];
    float v = 0.f;
    #pragma unroll
    for (int h = 0; h < 4; h++){
        float a = ws[O_AL1 + e*4 + h] / ws[O_DEN1 + (long)dst*4 + h];
        const float* W = ws + O_W1 + (long)(rt*2)*512 + h*128 + d;   // i=0 row; +512 -> i=1
        v += a * (xs0*W[0] + xs1*W[512]);
    }
    atomicAdd(&ws[O_AGG1 + (long)dst*128 + d], 0.25f * v);
}

// ---------------- h = selu(agg + b); optionally mirror to bf16 ----------------
__global__ void k_h(float* ws, long o_agg, long o_b, long o_dst, long o_bf){
    long i = (long)blockIdx.x*blockDim.x + threadIdx.x;
    if (i >= NN*128) return;
    int d = (int)(i & 127);
    float v = selu_f(ws[o_agg + i] + ws[o_b + d]);
    ws[o_dst + i] = v;
    if (o_bf >= 0) ((__hip_bfloat16*)(ws + o_bf))[i] = __float2bfloat16(v);
}

// ---------------- AQ/AK tables: AQ[n][r*4+h] = h1[n] . Wq2[r,:,h] ----------------
// block: 256 thr, 16 nodes; LDS: transposed weights [i][o] + padded h rows
__global__ void k_aqk(float* ws){
    __shared__ float wq[128*16];
    __shared__ float wk[128*16];
    __shared__ float hl[16][129];
    int tid = threadIdx.x;
    long nb = (long)blockIdx.x * 16;
    #pragma unroll
    for (int c = 0; c < 8; c++){
        int idx = tid + c*256;               // 0..2047
        int i = idx >> 4, o = idx & 15;
        int r = o >> 2, h = o & 3;
        wq[i*16 + o] = ws[O_WQ2 + r*512 + i*4 + h];
        wk[i*16 + o] = ws[O_WK2 + r*512 + i*4 + h];
        hl[idx >> 7][idx & 127] = ws[O_H1 + nb*128 + idx];
    }
    __syncthreads();
    int j = tid >> 4, o = tid & 15;
    float aq = 0.f, ak = 0.f;
    #pragma unroll 4
    for (int i = 0; i < 128; i++){
        float hv = hl[j][i];
        aq += hv * wq[i*16 + o];
        ak += hv * wk[i*16 + o];
    }
    ws[O_AQ + (nb + j)*16 + o] = aq;
    ws[O_AK + (nb + j)*16 + o] = ak;
}

// ---------------- layer 2 logits via AQ/AK tables (32 B/edge) ----------------
__global__ void k_alpha2_fast(const int* ei, const int* et, float* ws){
    long e = (long)blockIdx.x*blockDim.x + threadIdx.x;
    if (e >= NE) return;
    int src = ei[e], dst = ei[NE + e], rt = et[e];
    float4 q = *(const float4*)&ws[O_AQ + (long)dst*16 + rt*4];
    float4 k = *(const float4*)&ws[O_AK + (long)src*16 + rt*4];
    float4 al;
    al.x = lrelu_f(q.x + k.x);
    al.y = lrelu_f(q.y + k.y);
    al.z = lrelu_f(q.z + k.z);
    al.w = lrelu_f(q.w + k.w);
    *(float4*)&ws[O_AL2 + e*4] = al;
    unsigned* am = (unsigned*)(ws + O_AMAX2);
    atomicMax(&am[(long)dst*4 + 0], fkey(al.x));
    atomicMax(&am[(long)dst*4 + 1], fkey(al.y));
    atomicMax(&am[(long)dst*4 + 2], fkey(al.z));
    atomicMax(&am[(long)dst*4 + 3], fkey(al.w));
}

// ---------------- xw2 = h1 @ W2 via MFMA (bf16 in, f32 acc, bf16 table out) ----------------
__global__ void k_xw2_mfma(float* ws){
    __shared__ __align__(16) unsigned short Ash[128*128];   // 32 KB
    __shared__ __align__(16) unsigned short Bsh[128*128];   // 32 KB
    const unsigned short* h1b  = (const unsigned short*)(ws + O_H1B);
    const unsigned short* w2bt = (const unsigned short*)(ws + O_W2BT);
    long bm = (long)blockIdx.x * 128;
    long bn = (long)blockIdx.y * 128;
    int tid = threadIdx.x;
    char* Ac = (char*)Ash; char* Bc = (char*)Bsh;
    #pragma unroll
    for (int i = 0; i < 8; i++){
        int c = tid + i*256;                 // 0..2047 chunks of 16B
        int row = c >> 4, kb = (c & 15) * 16;
        int off = row*256 + (kb ^ ((row & 7) << 4));
        *(bf16x8*)(Ac + off) = *(const bf16x8*)&h1b [(bm + row)*128 + (c & 15)*8];
        *(bf16x8*)(Bc + off) = *(const bf16x8*)&w2bt[(bn + row)*128 + (c & 15)*8];
    }
    __syncthreads();
    int w = tid >> 6, lane = tid & 63;
    int wm = (w >> 1) * 64, wn = (w & 1) * 64;
    int r16 = lane & 15, kq = lane >> 4;
    f32x4 acc[4][4] = {};
    #pragma unroll
    for (int ks = 0; ks < 4; ks++){
        int kbyte = ks*64 + kq*16;
        bf16x8 a[4], b[4];
        #pragma unroll
        for (int m = 0; m < 4; m++){
            int row = wm + m*16 + r16;
            a[m] = *(const bf16x8*)(Ac + row*256 + (kbyte ^ ((row & 7) << 4)));
        }
        #pragma unroll
        for (int n = 0; n < 4; n++){
            int row = wn + n*16 + r16;
            b[n] = *(const bf16x8*)(Bc + row*256 + (kbyte ^ ((row & 7) << 4)));
        }
        #pragma unroll
        for (int m = 0; m < 4; m++)
            #pragma unroll
            for (int n = 0; n < 4; n++)
                acc[m][n] = __builtin_amdgcn_mfma_f32_16x16x32_bf16(a[m], b[n], acc[m][n], 0, 0, 0);
    }
    // C/D layout: col = lane&15, row = (lane>>4)*4 + reg
    __hip_bfloat16* xb = (__hip_bfloat16*)(ws + O_XW2);
    #pragma unroll
    for (int m = 0; m < 4; m++){
        long gr0 = bm + wm + m*16 + kq*4;
        #pragma unroll
        for (int j = 0; j < 4; j++){
            long gr = gr0 + j;
            if (gr < NN){
                #pragma unroll
                for (int n = 0; n < 4; n++){
                    long gc = bn + wn + n*16 + r16;
                    xb[gr*2048 + gc] = __float2bfloat16(acc[m][n][j]);
                }
            }
        }
    }
}

// ---------------- xw2 fallback (VALU) ----------------
__global__ void k_xw2(float* ws){
    __shared__ float hrow[16][128];
    long nb = (long)blockIdx.x * 16;
    int t = threadIdx.x;
    for (int k = 0; k < 8; k++){
        int idx = k*256 + t;
        hrow[idx >> 7][idx & 127] = ws[O_H1 + nb*128 + idx];
    }
    __syncthreads();
    __hip_bfloat16* xb = (__hip_bfloat16*)(ws + O_XW2);
    for (int k = 0; k < 8; k++){
        int o = k*256 + t;                  // 0..2047
        int r = o >> 9, oi = o & 511;
        const float* W = ws + O_W2 + (long)r*65536 + oi;   // stride 512 over i
        float acc[16];
        #pragma unroll
        for (int j = 0; j < 16; j++) acc[j] = 0.f;
        for (int i = 0; i < 128; i++){
            float w = W[(long)i*512];
            #pragma unroll
            for (int j = 0; j < 16; j++) acc[j] += hrow[j][i]*w;
        }
        for (int j = 0; j < 16; j++) xb[(nb + j)*2048 + o] = __float2bfloat16(acc[j]);
    }
}

// ---------------- layer 2 logits, fallback (row gathers) ----------------
__global__ void k_alpha2(const int* ei, const int* et, float* ws){
    long e = (long)blockIdx.x*blockDim.x + threadIdx.x;
    if (e >= NE) return;
    int src = ei[e], dst = ei[NE + e], rt = et[e];
    const float4* hs4 = (const float4*)(ws + O_H1 + (long)src*128);
    const float4* hd4 = (const float4*)(ws + O_H1 + (long)dst*128);
    const float* Wq = ws + O_WQ2 + (long)rt*512;   // [i*4+h]
    const float* Wk = ws + O_WK2 + (long)rt*512;
    float a[4] = {0.f,0.f,0.f,0.f};
    for (int i0 = 0; i0 < 32; i0++){
        float4 s4 = hs4[i0], d4 = hd4[i0];
        const float* wq = Wq + i0*16;
        const float* wk = Wk + i0*16;
        #pragma unroll
        for (int h = 0; h < 4; h++){
            a[h] += d4.x*wq[h] + d4.y*wq[4+h] + d4.z*wq[8+h] + d4.w*wq[12+h]
                  + s4.x*wk[h] + s4.y*wk[4+h] + s4.z*wk[8+h] + s4.w*wk[12+h];
        }
    }
    unsigned* am = (unsigned*)(ws + O_AMAX2);
    #pragma unroll
    for (int h = 0; h < 4; h++){
        float v = lrelu_f(a[h]);
        ws[O_AL2 + e*4 + h] = v;
        atomicMax(&am[(long)dst*4 + h], fkey(v));
    }
}

// ---------------- layer 2 messages via bf16 table ----------------
__global__ void k_msg2(const int* ei, const int* et, float* ws){
    int le = threadIdx.x >> 7, d = threadIdx.x & 127;
    long e = (long)blockIdx.x*2 + le;
    if (e >= NE) return;
    int src = ei[e], dst = ei[NE + e], rt = et[e];
    const __hip_bfloat16* xr = (const __hip_bfloat16*)(ws + O_XW2) + ((long)src*4 + rt)*512;
    float v = 0.f;
    #pragma unroll
    for (int h = 0; h < 4; h++){
        float a = ws[O_AL2 + e*4 + h] / ws[O_DEN2 + (long)dst*4 + h];
        v += a * __bfloat162float(xr[h*128 + d]);
    }
    atomicAdd(&ws[O_AGG2 + (long)dst*128 + d], 0.25f * v);
}

// ---------------- layer 2 messages, no-table fallback ----------------
__global__ void k_msg2_direct(const int* ei, const int* et, float* ws){
    __shared__ float hsrow[2][128];
    __shared__ float ash[2][4];
    int le = threadIdx.x >> 7, d = threadIdx.x & 127;
    long e = (long)blockIdx.x*2 + le;
    int src = 0, dst = 0, rt = 0;
    bool ok = (e < NE);
    if (ok){
        src = ei[e]; dst = ei[NE + e]; rt = et[e];
        hsrow[le][d] = ws[O_H1 + (long)src*128 + d];
        if (d < 4) ash[le][d] = ws[O_AL2 + e*4 + d] / ws[O_DEN2 + (long)dst*4 + d];
    }
    __syncthreads();
    if (!ok) return;
    float a0 = ash[le][0]*0.25f, a1 = ash[le][1]*0.25f, a2 = ash[le][2]*0.25f, a3 = ash[le][3]*0.25f;
    const float* W = ws + O_W2 + (long)rt*65536 + d;
    float v = 0.f;
    for (int i = 0; i < 128; i++){
        const float* Wi = W + (long)i*512;
        v += hsrow[le][i] * (a0*Wi[0] + a1*Wi[128] + a2*Wi[256] + a3*Wi[384]);
    }
    atomicAdd(&ws[O_AGG2 + (long)dst*128 + d], v);
}

// ---------------- global add pool ----------------
__global__ void k_pool(float* ws){
    int b = blockIdx.x, d = threadIdx.x;
    float s = 0.f;
    for (int j = 0; j < GN; j++) s += ws[O_H2 + ((long)b*GN + j)*128 + d];
    ws[O_G + (long)b*128 + d] = s;
}

// ---------------- cosine embedding + z = g * relu(cos @ cw^T + cb) ----------------
__global__ void k_cosz(float* ws){
    __shared__ float cs[64];
    int bt = blockIdx.x, t = threadIdx.x;
    if (t < 64){
        float tau = ws[O_TAU + bt];
        cs[t] = cosf(tau * (3.14159265358979323846f * (float)(t + 1)));
    }
    __syncthreads();
    int b = bt >> 3;   // T = 8
    const float* cw = ws + O_CW + (long)t*64;
    float s = ws[O_CB + t];
    for (int c = 0; c < 64; c++) s += cs[c]*cw[c];
    s = fmaxf(s, 0.f);
    ws[O_Z0 + (long)bt*128 + t] = ws[O_G + (long)b*128 + t] * s;
}

// ---------------- noisy FF layer: dst = selu(src @ W^T + B) ----------------
__global__ void k_ff(float* ws, long o_src, long o_w, long o_b, long o_dst){
    __shared__ float row[128];
    int bt = blockIdx.x, t = threadIdx.x;
    row[t] = ws[o_src + (long)bt*128 + t];
    __syncthreads();
    const float* W = ws + o_w + (long)t*128;
    float s = ws[o_b + t];
    for (int i = 0; i < 128; i++) s += row[i]*W[i];
    ws[o_dst + (long)bt*128 + t] = selu_f(s);
}

// ---------------- dueling head + taus passthrough ----------------
__global__ void k_head(float* ws, void* d_out, const void* taus_raw){
    __shared__ float row[128];
    __shared__ float advs[12];
    int bt = blockIdx.x, t = threadIdx.x;
    row[t] = ws[O_Z2 + (long)bt*128 + t];
    row[64 + t] = ws[O_Z2 + (long)bt*128 + 64 + t];
    __syncthreads();
    if (t < 11){
        const float* W = (t < 10) ? (ws + O_CAW + (long)t*128) : (ws + O_CVW);
        float s = (t < 10) ? ws[O_CAB + t] : ws[O_CVB];
        for (int i = 0; i < 128; i++) s += row[i]*W[i];
        advs[t] = s;
    }
    __syncthreads();
    if (t == 0){
        float m = 0.f;
        #pragma unroll
        for (int a = 0; a < 10; a++) m += advs[a];
        m *= 0.1f;
        float val = advs[10];
        int bf = ((const int*)ws)[0];
        if (bf){
            __hip_bfloat16* out = (__hip_bfloat16*)d_out;
            for (int a = 0; a < 10; a++) out[(long)bt*10 + a] = __float2bfloat16(val + advs[a] - m);
            ((unsigned short*)d_out)[16000 + bt] = ((const unsigned short*)taus_raw)[bt];
        } else {
            float* out = (float*)d_out;
            for (int a = 0; a < 10; a++) out[(long)bt*10 + a] = val + advs[a] - m;
            out[16000 + bt] = ((const float*)taus_raw)[bt];
        }
    }
}

// ---------------- launch ----------------
extern "C" void kernel_launch(void* const* d_in, const int* in_sizes, int n_in,
                              void* d_out, int out_size, void* d_ws, size_t ws_size,
                              hipStream_t stream){
    (void)in_sizes; (void)n_in; (void)out_size;
    float* ws = (float*)d_ws;
    const int* ei = (const int*)d_in[1];
    const int* et = (const int*)d_in[2];

    bool use_aqk   = ws_size >= (size_t)O_END3*4;
    bool use_mfma  = ws_size >= (size_t)O_END2*4;
    bool use_table = ws_size >= (size_t)O_END_TABLE*4;

    // zero atomic-target region (agg1, agg2, den1, den2, amax1, amax2)
    hipMemsetAsync(ws + O_AGG1, 0, (size_t)ZERO_CNT*4, stream);

    // mode detect + input conversion
    k_detect<<<1, 64, 0, stream>>>((const unsigned short*)d_in[3], (int*)d_ws);

    ConvArgs ca;
    static const long conv_o[38] = {
        O_X, -1, -1, O_TAU, O_W1, O_Q1, O_K1, O_B1, O_W2, O_Q2, O_K2, O_B2, O_CW, O_CB,
        O_F1W, O_F1B, O_F1SW, O_F1SB, O_F1EW, O_F1EB,
        O_F2W, O_F2B, O_F2SW, O_F2SB, O_F2EW, O_F2EB,
        O_AW, O_AB, O_ASW, O_ASB, O_AEW, O_AEB,
        O_VW, O_VB, O_VSW, O_VSB, O_VEW, O_VEB };
    static const int conv_n[38] = {
        40000, 0, 0, 1600, 4096, 2048, 2048, 128, 262144, 2048, 2048, 128, 8192, 128,
        16384, 128, 16384, 128, 16384, 128,
        16384, 128, 16384, 128, 16384, 128,
        1280, 10, 1280, 10, 1280, 10,
        128, 1, 128, 1, 128, 1 };
    for (int i = 0; i < 38; i++){ ca.src[i] = d_in[i]; ca.off[i] = conv_o[i]; ca.n[i] = conv_n[i]; }
    k_convert<<<dim3(128, 38), 256, 0, stream>>>(ca, ws);

    k_fold<<<dim3(8, 4), 256, 0, stream>>>(ws);
    k_noisy<<<dim3(64, 8), 256, 0, stream>>>(ws);
    if (use_mfma){
        k_w2b<<<1024, 256, 0, stream>>>(ws);
        k_zpad<<<24, 256, 0, stream>>>(ws);
    }

    // ---- RGAT layer 1 ----
    k_alpha1<<<625, 256, 0, stream>>>(ei, et, ws);
    k_ex<<<625, 256, 0, stream>>>(ei, ws, O_AL1, O_AMAX1, O_DEN1);
    k_msg1<<<80000, 256, 0, stream>>>(ei, et, ws);
    k_h<<<10000, 256, 0, stream>>>(ws, O_AGG1, O_B1, O_H1, use_mfma ? O_H1B : -1);

    // ---- RGAT layer 2 ----
    if (use_mfma)       k_xw2_mfma<<<dim3(157, 16), 256, 0, stream>>>(ws);
    else if (use_table) k_xw2<<<1250, 256, 0, stream>>>(ws);
    if (use_aqk){
        k_aqk<<<1250, 256, 0, stream>>>(ws);
        k_alpha2_fast<<<625, 256, 0, stream>>>(ei, et, ws);
    } else {
        k_alpha2<<<625, 256, 0, stream>>>(ei, et, ws);
    }
    k_ex<<<625, 256, 0, stream>>>(ei, ws, O_AL2, O_AMAX2, O_DEN2);
    if (use_table) k_msg2<<<80000, 256, 0, stream>>>(ei, et, ws);
    else           k_msg2_direct<<<80000, 256, 0, stream>>>(ei, et, ws);
    k_h<<<10000, 256, 0, stream>>>(ws, O_AGG2, O_B2, O_H2, -1);

    // ---- head ----
    k_pool<<<200, 128, 0, stream>>>(ws);
    k_cosz<<<1600, 128, 0, stream>>>(ws);
    k_ff<<<1600, 128, 0, stream>>>(ws, O_Z0, O_CF1W, O_CF1B, O_Z1);
    k_ff<<<1600, 128, 0, stream>>>(ws, O_Z1, O_CF2W, O_CF2B, O_Z2);
    k_head<<<1600, 64, 0, stream>>>(ws, d_out, d_in[3]);
}

// Round 4
// 262.082 us; speedup vs baseline: 2.5816x; 1.6557x over previous
//
#include <hip/hip_runtime.h>
#include <hip/hip_bf16.h>

// ---------------- problem constants ----------------
constexpr long NN = 20000;   // nodes
constexpr long NE = 160000;  // edges
constexpr long BB = 200;     // graphs
constexpr long TT = 8;       // taus
constexpr long GN = 100;     // nodes per graph

// ---------------- ws layout (f32 element offsets) ----------------
constexpr long O_FLAG = 0;                                      // int mode flag
constexpr long O_X    = 16;                 constexpr long N_X   = 40000;
constexpr long O_TAU  = O_X + N_X;          constexpr long N_TAU = 1600;
constexpr long O_W1   = O_TAU + N_TAU;      constexpr long N_W1  = 4096;
constexpr long O_Q1   = O_W1 + N_W1;        constexpr long N_Q   = 2048;
constexpr long O_K1   = O_Q1 + N_Q;
constexpr long O_B1   = O_K1 + N_Q;         constexpr long N_B   = 128;
constexpr long O_W2   = O_B1 + N_B;         constexpr long N_W2  = 262144;
constexpr long O_Q2   = O_W2 + N_W2;
constexpr long O_K2   = O_Q2 + N_Q;
constexpr long O_B2   = O_K2 + N_Q;
constexpr long O_CW   = O_B2 + N_B;         constexpr long N_CW  = 8192;
constexpr long O_CB   = O_CW + N_CW;
constexpr long O_F1W  = O_CB + N_B;         constexpr long N_FW  = 16384;
constexpr long O_F1B  = O_F1W + N_FW;
constexpr long O_F1SW = O_F1B + N_B;
constexpr long O_F1SB = O_F1SW + N_FW;
constexpr long O_F1EW = O_F1SB + N_B;
constexpr long O_F1EB = O_F1EW + N_FW;
constexpr long O_F2W  = O_F1EB + N_B;
constexpr long O_F2B  = O_F2W + N_FW;
constexpr long O_F2SW = O_F2B + N_B;
constexpr long O_F2SB = O_F2SW + N_FW;
constexpr long O_F2EW = O_F2SB + N_B;
constexpr long O_F2EB = O_F2EW + N_FW;
constexpr long O_AW   = O_F2EB + N_B;       constexpr long N_AW  = 1280;
constexpr long O_AB   = O_AW + N_AW;        constexpr long N_AB  = 16;  // 10 used
constexpr long O_ASW  = O_AB + N_AB;
constexpr long O_ASB  = O_ASW + N_AW;
constexpr long O_AEW  = O_ASB + N_AB;
constexpr long O_AEB  = O_AEW + N_AW;
constexpr long O_VW   = O_AEB + N_AB;       constexpr long N_VW  = 128;
constexpr long O_VB   = O_VW + N_VW;        constexpr long N_VB  = 16;  // 1 used
constexpr long O_VSW  = O_VB + N_VB;
constexpr long O_VSB  = O_VSW + N_VW;
constexpr long O_VEW  = O_VSB + N_VB;
constexpr long O_VEB  = O_VEW + N_VW;
// derived
constexpr long O_WQ1  = O_VEB + N_VB;       // [4][2][4] = 32  (r*8 + i*4 + h)
constexpr long O_WK1  = O_WQ1 + 32;
constexpr long O_WQ2  = O_WK1 + 32;         // [4][128][4] = 2048
constexpr long O_WK2  = O_WQ2 + 2048;
constexpr long O_CF1W = O_WK2 + 2048;       // combined noisy weights
constexpr long O_CF1B = O_CF1W + N_FW;
constexpr long O_CF2W = O_CF1B + N_B;
constexpr long O_CF2B = O_CF2W + N_FW;
constexpr long O_CAW  = O_CF2B + N_B;
constexpr long O_CAB  = O_CAW + N_AW;
constexpr long O_CVW  = O_CAB + N_AB;
constexpr long O_CVB  = O_CVW + N_VW;
constexpr long O_AL1  = O_CVB + N_VB;       // [E][4] (unused now, kept for layout stability)
constexpr long O_AL2  = O_AL1 + NE*4;
constexpr long O_H1   = O_AL2 + NE*4;       // [N][128]
constexpr long O_H2   = O_H1 + NN*128;
constexpr long O_G    = O_H2 + NN*128;      // [200][128]
constexpr long O_Z0   = O_G + BB*128;       // [1600][128]
constexpr long O_Z1   = O_Z0 + BB*TT*128;
constexpr long O_Z2   = O_Z1 + BB*TT*128;
// former atomic region, reused for CSR (int-typed)
constexpr long O_AGG1 = O_Z2 + BB*TT*128;   // 2.56M f32 slots available here
constexpr long O_DEG  = O_AGG1;             // [NN] int
constexpr long O_CUR  = O_DEG + NN;         // [NN] int
constexpr long O_ROWP = O_CUR + NN;         // [NN+1] int (+pad)
constexpr long O_PERM = O_ROWP + NN + 8;    // [NE] int
constexpr long O_AGG2 = O_AGG1 + NN*128;
constexpr long O_DEN1 = O_AGG2 + NN*128;
constexpr long O_DEN2 = O_DEN1 + NN*4;
constexpr long O_AMAX1= O_DEN2 + NN*4;
constexpr long O_AMAX2= O_AMAX1 + NN*4;
// bf16 xw2 table [N][4][512] (viewed as u16)
constexpr long O_XW2  = O_AMAX2 + NN*4;
constexpr long O_END_TABLE = O_XW2 + (NN*4*512)/2;
// MFMA-path extras: h1 in bf16 (padded to 20096 rows), W2 transposed bf16
constexpr long MPAD   = 20096;
constexpr long O_H1B  = O_END_TABLE;                  // [20096][128] bf16
constexpr long O_W2BT = O_H1B + (MPAD*128)/2;         // [2048][128] bf16  Bt[n][k]
constexpr long O_END2 = O_W2BT + (2048L*128)/2;
// AQ/AK tables: [N][16] f32, idx = r*4+h
constexpr long O_AQ   = O_END2;
constexpr long O_AK   = O_AQ + NN*16;
constexpr long O_END3 = O_AK + NN*16;

constexpr int EMAX = 128;   // per-node cached edge slots (P(deg>128) ~ 0; fallback recomputes)

#define DEVFN __device__ __forceinline__

typedef __attribute__((ext_vector_type(8))) short bf16x8;
typedef __attribute__((ext_vector_type(4))) float f32x4;

DEVFN float selu_f(float x){ return 1.0507009873554805f * (x > 0.f ? x : 1.6732632423543772f * expm1f(x)); }
DEVFN float lrelu_f(float x){ return x >= 0.f ? x : 0.2f * x; }
DEVFN float bf2f(unsigned short u){ return __uint_as_float(((unsigned)u) << 16); }

// ---------------- mode detection ----------------
__global__ void k_detect(const unsigned short* taus_u16, int* flag){
    if (threadIdx.x == 0){
        int bf = 1;
        for (int i = 0; i < 128; i++){
            if (taus_u16[i] > 0x3F80u){ bf = 0; break; }
        }
        *flag = bf;
    }
}

// ---------------- convert all float inputs to f32 in ws ----------------
struct ConvArgs { const void* src[38]; long off[38]; int n[38]; };

__global__ void k_convert(ConvArgs a, float* ws){
    int arr = blockIdx.y;
    long off = a.off[arr];
    if (off < 0) return;
    const void* s = a.src[arr];
    int n = a.n[arr];
    int bf = ((const int*)ws)[0];
    for (int i = blockIdx.x*blockDim.x + threadIdx.x; i < n; i += gridDim.x*blockDim.x){
        float v;
        if (bf){ unsigned short u = ((const unsigned short*)s)[i]; v = bf2f(u); }
        else   { v = ((const float*)s)[i]; }
        ws[off + i] = v;
    }
}

// ---------------- CSR build ----------------
__global__ void k_hist(const int* ei, float* ws){
    long e = (long)blockIdx.x*blockDim.x + threadIdx.x;
    if (e >= NE) return;
    atomicAdd((int*)(ws + O_DEG) + ei[NE + e], 1);
}

__global__ void k_scan(float* ws){
    const int* deg = (const int*)(ws + O_DEG);
    int* rowp = (int*)(ws + O_ROWP);
    __shared__ int part[256];
    int tid = threadIdx.x;
    int base = tid * 79;
    int n = 0; if (base < NN) n = min(79, (int)NN - base);
    int s = 0;
    for (int i = 0; i < n; i++) s += deg[base + i];
    part[tid] = s;
    __syncthreads();
    if (tid == 0){
        int acc = 0;
        for (int i = 0; i < 256; i++){ int t = part[i]; part[i] = acc; acc += t; }
    }
    __syncthreads();
    int acc = part[tid];
    for (int i = 0; i < n; i++){ rowp[base + i] = acc; acc += deg[base + i]; }
    if (tid == 0) rowp[NN] = (int)NE;
}

__global__ void k_scatter(const int* ei, float* ws){
    long e = (long)blockIdx.x*blockDim.x + threadIdx.x;
    if (e >= NE) return;
    int dst = ei[NE + e];
    int pos = atomicAdd((int*)(ws + O_CUR) + dst, 1);
    ((int*)(ws + O_PERM))[((const int*)(ws + O_ROWP))[dst] + pos] = (int)e;
}

// ---------------- fold W@q / W@k ----------------
__global__ void k_fold(float* ws){
    int task = blockIdx.y;
    int idx = blockIdx.x*blockDim.x + threadIdx.x;
    if (task < 2){
        if (idx >= 32) return;
        int h = idx & 3, ri = idx >> 2;
        const float* W = ws + O_W1 + (long)ri*512;
        const float* Q = ws + (task == 0 ? O_Q1 : O_K1);
        float s = 0.f;
        for (int o = 0; o < 512; o++) s += W[o] * Q[o*4 + h];
        ws[(task == 0 ? O_WQ1 : O_WK1) + idx] = s;
    } else {
        if (idx >= 2048) return;
        int h = idx & 3, ri = idx >> 2;
        const float* W = ws + O_W2 + (long)ri*512;
        const float* Q = ws + (task == 2 ? O_Q2 : O_K2);
        float s = 0.f;
        for (int o = 0; o < 512; o++) s += W[o] * Q[o*4 + h];
        ws[(task == 2 ? O_WQ2 : O_WK2) + idx] = s;
    }
}

// ---------------- combine noisy weights ----------------
__global__ void k_noisy(float* ws){
    const long tw[8] = {O_F1W,O_F2W,O_AW,O_VW, O_F1B,O_F2B,O_AB,O_VB};
    const long ts[8] = {O_F1SW,O_F2SW,O_ASW,O_VSW, O_F1SB,O_F2SB,O_ASB,O_VSB};
    const long te[8] = {O_F1EW,O_F2EW,O_AEW,O_VEW, O_F1EB,O_F2EB,O_AEB,O_VEB};
    const long td[8] = {O_CF1W,O_CF2W,O_CAW,O_CVW, O_CF1B,O_CF2B,O_CAB,O_CVB};
    const int  tn[8] = {16384,16384,1280,128, 128,128,10,1};
    int t = blockIdx.y;
    for (int i = blockIdx.x*blockDim.x + threadIdx.x; i < tn[t]; i += gridDim.x*blockDim.x)
        ws[td[t] + i] = ws[tw[t] + i] + ws[ts[t] + i]*ws[te[t] + i];
}

// ---------------- W2 -> Bt[n][k] bf16 ----------------
__global__ void k_w2b(float* ws){
    int idx = blockIdx.x*blockDim.x + threadIdx.x;
    int n = idx & 2047, k = idx >> 11;
    float v = ws[O_W2 + (long)(n >> 9)*65536 + (long)k*512 + (n & 511)];
    ((__hip_bfloat16*)(ws + O_W2BT))[(long)n*128 + k] = __float2bfloat16(v);
}

__global__ void k_zpad(float* ws){
    int i = blockIdx.x*blockDim.x + threadIdx.x;
    if (i < 6144) ws[O_H1B + (20000L*128)/2 + i] = 0.f;
}

// ---------------- fused layer-1 node kernel ----------------
// One node per 128-thread block: alpha + softmax + factored message + bias + selu.
__global__ void k_node1(const int* ei, const int* et, float* ws){
    __shared__ float wqk[64];          // WQ1(32) ++ WK1(32), contiguous
    __shared__ float alc[EMAX][4];
    __shared__ float xsc[EMAX][2];
    __shared__ int   rtc[EMAX];
    __shared__ float sacc[4][4][2];    // [r][h][i]
    __shared__ float den[4], amax[4];
    __shared__ float mred[2][4];
    int n = blockIdx.x, tid = threadIdx.x;
    const int* rowp = (const int*)(ws + O_ROWP);
    const int* perm = (const int*)(ws + O_PERM);
    int e0 = rowp[n], deg = rowp[n+1] - e0;
    if (tid < 64) wqk[tid] = ws[O_WQ1 + tid];
    if (tid < 32) ((float*)sacc)[tid] = 0.f;
    if (tid < 4) den[tid] = 0.f;
    float xd0 = ws[O_X + (long)n*2], xd1 = ws[O_X + (long)n*2 + 1];
    __syncthreads();
    // pass 1: alpha + running max
    float mx[4] = {-3.0e38f,-3.0e38f,-3.0e38f,-3.0e38f};
    for (int j0 = 0; j0 < deg; j0 += 128){
        int j = j0 + tid;
        if (j < deg){
            int e = perm[e0 + j];
            int src = ei[e], rt = et[e];
            float xs0 = ws[O_X + (long)src*2], xs1 = ws[O_X + (long)src*2 + 1];
            const float* Wq = wqk + rt*8;
            const float* Wk = wqk + 32 + rt*8;
            #pragma unroll
            for (int h = 0; h < 4; h++){
                float a = lrelu_f(xd0*Wq[h] + xd1*Wq[4+h] + xs0*Wk[h] + xs1*Wk[4+h]);
                if (j < EMAX) alc[j][h] = a;
                mx[h] = fmaxf(mx[h], a);
            }
            if (j < EMAX){ xsc[j][0] = xs0; xsc[j][1] = xs1; rtc[j] = rt; }
        }
    }
    #pragma unroll
    for (int off = 32; off > 0; off >>= 1)
        #pragma unroll
        for (int h = 0; h < 4; h++) mx[h] = fmaxf(mx[h], __shfl_xor(mx[h], off));
    if ((tid & 63) == 0)
        #pragma unroll
        for (int h = 0; h < 4; h++) mred[tid >> 6][h] = mx[h];
    __syncthreads();
    if (tid < 4) amax[tid] = fmaxf(mred[0][tid], mred[1][tid]);
    __syncthreads();
    // pass 2: exp + den + factored scalars
    for (int j0 = 0; j0 < deg; j0 += 128){
        int j = j0 + tid;
        if (j < deg){
            float al[4], xs0, xs1; int rt;
            if (j < EMAX){
                #pragma unroll
                for (int h = 0; h < 4; h++) al[h] = alc[j][h];
                xs0 = xsc[j][0]; xs1 = xsc[j][1]; rt = rtc[j];
            } else {
                int e = perm[e0 + j];
                int src = ei[e]; rt = et[e];
                xs0 = ws[O_X + (long)src*2]; xs1 = ws[O_X + (long)src*2 + 1];
                const float* Wq = wqk + rt*8;
                const float* Wk = wqk + 32 + rt*8;
                #pragma unroll
                for (int h = 0; h < 4; h++)
                    al[h] = lrelu_f(xd0*Wq[h] + xd1*Wq[4+h] + xs0*Wk[h] + xs1*Wk[4+h]);
            }
            #pragma unroll
            for (int h = 0; h < 4; h++){
                float ex = expf(al[h] - amax[h]);
                atomicAdd(&den[h], ex);
                atomicAdd(&sacc[rt][h][0], ex*xs0);
                atomicAdd(&sacc[rt][h][1], ex*xs1);
            }
        }
    }
    __syncthreads();
    // pass 3: output
    int d = tid;
    float rden[4];
    #pragma unroll
    for (int h = 0; h < 4; h++) rden[h] = den[h] > 0.f ? 0.25f/den[h] : 0.f;
    float v = 0.f;
    #pragma unroll
    for (int r = 0; r < 4; r++)
        #pragma unroll
        for (int h = 0; h < 4; h++){
            float w0 = ws[O_W1 + r*1024 +        h*128 + d];
            float w1 = ws[O_W1 + r*1024 + 512  + h*128 + d];
            v += rden[h]*(w0*sacc[r][h][0] + w1*sacc[r][h][1]);
        }
    float out = selu_f(v + ws[O_B1 + d]);
    ws[O_H1 + (long)n*128 + d] = out;
    ((__hip_bfloat16*)(ws + O_H1B))[(long)n*128 + d] = __float2bfloat16(out);
}

// ---------------- AQ/AK tables: AQ[n][r*4+h] = h1[n] . Wq2[r,:,h] ----------------
__global__ void k_aqk(float* ws){
    __shared__ float wq[128*16];
    __shared__ float wk[128*16];
    __shared__ float hl[16][129];
    int tid = threadIdx.x;
    long nb = (long)blockIdx.x * 16;
    #pragma unroll
    for (int c = 0; c < 8; c++){
        int idx = tid + c*256;
        int i = idx >> 4, o = idx & 15;
        int r = o >> 2, h = o & 3;
        wq[i*16 + o] = ws[O_WQ2 + r*512 + i*4 + h];
        wk[i*16 + o] = ws[O_WK2 + r*512 + i*4 + h];
        hl[idx >> 7][idx & 127] = ws[O_H1 + nb*128 + idx];
    }
    __syncthreads();
    int j = tid >> 4, o = tid & 15;
    float aq = 0.f, ak = 0.f;
    #pragma unroll 4
    for (int i = 0; i < 128; i++){
        float hv = hl[j][i];
        aq += hv * wq[i*16 + o];
        ak += hv * wk[i*16 + o];
    }
    ws[O_AQ + (nb + j)*16 + o] = aq;
    ws[O_AK + (nb + j)*16 + o] = ak;
}

// ---------------- xw2 = h1 @ W2 via MFMA ----------------
__global__ void k_xw2_mfma(float* ws){
    __shared__ __align__(16) unsigned short Ash[128*128];
    __shared__ __align__(16) unsigned short Bsh[128*128];
    const unsigned short* h1b  = (const unsigned short*)(ws + O_H1B);
    const unsigned short* w2bt = (const unsigned short*)(ws + O_W2BT);
    long bm = (long)blockIdx.x * 128;
    long bn = (long)blockIdx.y * 128;
    int tid = threadIdx.x;
    char* Ac = (char*)Ash; char* Bc = (char*)Bsh;
    #pragma unroll
    for (int i = 0; i < 8; i++){
        int c = tid + i*256;
        int row = c >> 4, kb = (c & 15) * 16;
        int off = row*256 + (kb ^ ((row & 7) << 4));
        *(bf16x8*)(Ac + off) = *(const bf16x8*)&h1b [(bm + row)*128 + (c & 15)*8];
        *(bf16x8*)(Bc + off) = *(const bf16x8*)&w2bt[(bn + row)*128 + (c & 15)*8];
    }
    __syncthreads();
    int w = tid >> 6, lane = tid & 63;
    int wm = (w >> 1) * 64, wn = (w & 1) * 64;
    int r16 = lane & 15, kq = lane >> 4;
    f32x4 acc[4][4] = {};
    #pragma unroll
    for (int ks = 0; ks < 4; ks++){
        int kbyte = ks*64 + kq*16;
        bf16x8 a[4], b[4];
        #pragma unroll
        for (int m = 0; m < 4; m++){
            int row = wm + m*16 + r16;
            a[m] = *(const bf16x8*)(Ac + row*256 + (kbyte ^ ((row & 7) << 4)));
        }
        #pragma unroll
        for (int n = 0; n < 4; n++){
            int row = wn + n*16 + r16;
            b[n] = *(const bf16x8*)(Bc + row*256 + (kbyte ^ ((row & 7) << 4)));
        }
        #pragma unroll
        for (int m = 0; m < 4; m++)
            #pragma unroll
            for (int n = 0; n < 4; n++)
                acc[m][n] = __builtin_amdgcn_mfma_f32_16x16x32_bf16(a[m], b[n], acc[m][n], 0, 0, 0);
    }
    __hip_bfloat16* xb = (__hip_bfloat16*)(ws + O_XW2);
    #pragma unroll
    for (int m = 0; m < 4; m++){
        long gr0 = bm + wm + m*16 + kq*4;
        #pragma unroll
        for (int j = 0; j < 4; j++){
            long gr = gr0 + j;
            if (gr < NN){
                #pragma unroll
                for (int n = 0; n < 4; n++){
                    long gc = bn + wn + n*16 + r16;
                    xb[gr*2048 + gc] = __float2bfloat16(acc[m][n][j]);
                }
            }
        }
    }
}

// ---------------- fused layer-2 node kernel ----------------
__global__ void k_node2(const int* ei, const int* et, float* ws){
    __shared__ float aq[16];
    __shared__ float exc[EMAX][4];     // al, then ex
    __shared__ int   esrt[EMAX];       // src*4 + rt
    __shared__ float den[4], amax[4];
    __shared__ float mred[2][4];
    int n = blockIdx.x, tid = threadIdx.x;
    const int* rowp = (const int*)(ws + O_ROWP);
    const int* perm = (const int*)(ws + O_PERM);
    int e0 = rowp[n], deg = rowp[n+1] - e0;
    if (tid < 16) aq[tid] = ws[O_AQ + (long)n*16 + tid];
    if (tid < 4) den[tid] = 0.f;
    __syncthreads();
    // pass 1: alpha from AQ/AK + running max
    float mx[4] = {-3.0e38f,-3.0e38f,-3.0e38f,-3.0e38f};
    for (int j0 = 0; j0 < deg; j0 += 128){
        int j = j0 + tid;
        if (j < deg){
            int e = perm[e0 + j];
            int src = ei[e], rt = et[e];
            float4 k4 = *(const float4*)&ws[O_AK + (long)src*16 + rt*4];
            float al0 = lrelu_f(aq[rt*4+0] + k4.x);
            float al1 = lrelu_f(aq[rt*4+1] + k4.y);
            float al2 = lrelu_f(aq[rt*4+2] + k4.z);
            float al3 = lrelu_f(aq[rt*4+3] + k4.w);
            if (j < EMAX){
                exc[j][0]=al0; exc[j][1]=al1; exc[j][2]=al2; exc[j][3]=al3;
                esrt[j] = src*4 + rt;
            }
            mx[0]=fmaxf(mx[0],al0); mx[1]=fmaxf(mx[1],al1);
            mx[2]=fmaxf(mx[2],al2); mx[3]=fmaxf(mx[3],al3);
        }
    }
    #pragma unroll
    for (int off = 32; off > 0; off >>= 1)
        #pragma unroll
        for (int h = 0; h < 4; h++) mx[h] = fmaxf(mx[h], __shfl_xor(mx[h], off));
    if ((tid & 63) == 0)
        #pragma unroll
        for (int h = 0; h < 4; h++) mred[tid >> 6][h] = mx[h];
    __syncthreads();
    if (tid < 4) amax[tid] = fmaxf(mred[0][tid], mred[1][tid]);
    __syncthreads();
    // pass 2: exp + den (cache ex in LDS)
    for (int j0 = 0; j0 < deg; j0 += 128){
        int j = j0 + tid;
        if (j < deg && j < EMAX){
            #pragma unroll
            for (int h = 0; h < 4; h++){
                float ex = expf(exc[j][h] - amax[h]);
                exc[j][h] = ex;
                atomicAdd(&den[h], ex);
            }
        } else if (j < deg){
            int e = perm[e0 + j];
            int src = ei[e], rt = et[e];
            float4 k4 = *(const float4*)&ws[O_AK + (long)src*16 + rt*4];
            float al[4] = {lrelu_f(aq[rt*4+0]+k4.x), lrelu_f(aq[rt*4+1]+k4.y),
                           lrelu_f(aq[rt*4+2]+k4.z), lrelu_f(aq[rt*4+3]+k4.w)};
            #pragma unroll
            for (int h = 0; h < 4; h++) atomicAdd(&den[h], expf(al[h]-amax[h]));
        }
    }
    __syncthreads();
    // pass 3: gather table rows, accumulate
    int d = tid;
    const unsigned short* xw2 = (const unsigned short*)(ws + O_XW2);
    float acc[4] = {0.f,0.f,0.f,0.f};
    for (int j = 0; j < deg; j++){
        float ex[4]; long sr;
        if (j < EMAX){
            ex[0]=exc[j][0]; ex[1]=exc[j][1]; ex[2]=exc[j][2]; ex[3]=exc[j][3];
            sr = esrt[j];
        } else {
            int e = perm[e0 + j];
            int src = ei[e], rt = et[e];
            float4 k4 = *(const float4*)&ws[O_AK + (long)src*16 + rt*4];
            ex[0]=expf(lrelu_f(aq[rt*4+0]+k4.x)-amax[0]);
            ex[1]=expf(lrelu_f(aq[rt*4+1]+k4.y)-amax[1]);
            ex[2]=expf(lrelu_f(aq[rt*4+2]+k4.z)-amax[2]);
            ex[3]=expf(lrelu_f(aq[rt*4+3]+k4.w)-amax[3]);
            sr = (long)src*4 + rt;
        }
        const unsigned short* row = xw2 + sr*512;
        #pragma unroll
        for (int h = 0; h < 4; h++) acc[h] += ex[h]*bf2f(row[h*128 + d]);
    }
    float v = 0.f;
    #pragma unroll
    for (int h = 0; h < 4; h++){
        float rden = den[h] > 0.f ? 0.25f/den[h] : 0.f;
        v += acc[h]*rden;
    }
    ws[O_H2 + (long)n*128 + d] = selu_f(v + ws[O_B2 + d]);
}

// ---------------- global add pool ----------------
__global__ void k_pool(float* ws){
    int b = blockIdx.x, d = threadIdx.x;
    float s = 0.f;
    for (int j = 0; j < GN; j++) s += ws[O_H2 + ((long)b*GN + j)*128 + d];
    ws[O_G + (long)b*128 + d] = s;
}

// ---------------- cosine embedding + z ----------------
__global__ void k_cosz(float* ws){
    __shared__ float cs[64];
    int bt = blockIdx.x, t = threadIdx.x;
    if (t < 64){
        float tau = ws[O_TAU + bt];
        cs[t] = cosf(tau * (3.14159265358979323846f * (float)(t + 1)));
    }
    __syncthreads();
    int b = bt >> 3;
    const float* cw = ws + O_CW + (long)t*64;
    float s = ws[O_CB + t];
    for (int c = 0; c < 64; c++) s += cs[c]*cw[c];
    s = fmaxf(s, 0.f);
    ws[O_Z0 + (long)bt*128 + t] = ws[O_G + (long)b*128 + t] * s;
}

// ---------------- noisy FF layer ----------------
__global__ void k_ff(float* ws, long o_src, long o_w, long o_b, long o_dst){
    __shared__ float row[128];
    int bt = blockIdx.x, t = threadIdx.x;
    row[t] = ws[o_src + (long)bt*128 + t];
    __syncthreads();
    const float* W = ws + o_w + (long)t*128;
    float s = ws[o_b + t];
    for (int i = 0; i < 128; i++) s += row[i]*W[i];
    ws[o_dst + (long)bt*128 + t] = selu_f(s);
}

// ---------------- dueling head + taus passthrough ----------------
__global__ void k_head(float* ws, void* d_out, const void* taus_raw){
    __shared__ float row[128];
    __shared__ float advs[12];
    int bt = blockIdx.x, t = threadIdx.x;
    row[t] = ws[O_Z2 + (long)bt*128 + t];
    row[64 + t] = ws[O_Z2 + (long)bt*128 + 64 + t];
    __syncthreads();
    if (t < 11){
        const float* W = (t < 10) ? (ws + O_CAW + (long)t*128) : (ws + O_CVW);
        float s = (t < 10) ? ws[O_CAB + t] : ws[O_CVB];
        for (int i = 0; i < 128; i++) s += row[i]*W[i];
        advs[t] = s;
    }
    __syncthreads();
    if (t == 0){
        float m = 0.f;
        #pragma unroll
        for (int a = 0; a < 10; a++) m += advs[a];
        m *= 0.1f;
        float val = advs[10];
        int bf = ((const int*)ws)[0];
        if (bf){
            __hip_bfloat16* out = (__hip_bfloat16*)d_out;
            for (int a = 0; a < 10; a++) out[(long)bt*10 + a] = __float2bfloat16(val + advs[a] - m);
            ((unsigned short*)d_out)[16000 + bt] = ((const unsigned short*)taus_raw)[bt];
        } else {
            float* out = (float*)d_out;
            for (int a = 0; a < 10; a++) out[(long)bt*10 + a] = val + advs[a] - m;
            out[16000 + bt] = ((const float*)taus_raw)[bt];
        }
    }
}

// ---------------- launch ----------------
extern "C" void kernel_launch(void* const* d_in, const int* in_sizes, int n_in,
                              void* d_out, int out_size, void* d_ws, size_t ws_size,
                              hipStream_t stream){
    (void)in_sizes; (void)n_in; (void)out_size; (void)ws_size;
    float* ws = (float*)d_ws;
    const int* ei = (const int*)d_in[1];
    const int* et = (const int*)d_in[2];

    // zero CSR deg + cursor
    hipMemsetAsync(ws + O_DEG, 0, (size_t)(2*NN)*4, stream);

    k_detect<<<1, 64, 0, stream>>>((const unsigned short*)d_in[3], (int*)d_ws);

    // CSR build (independent of float conversion)
    k_hist<<<625, 256, 0, stream>>>(ei, ws);
    k_scan<<<1, 256, 0, stream>>>(ws);
    k_scatter<<<625, 256, 0, stream>>>(ei, ws);

    ConvArgs ca;
    static const long conv_o[38] = {
        O_X, -1, -1, O_TAU, O_W1, O_Q1, O_K1, O_B1, O_W2, O_Q2, O_K2, O_B2, O_CW, O_CB,
        O_F1W, O_F1B, O_F1SW, O_F1SB, O_F1EW, O_F1EB,
        O_F2W, O_F2B, O_F2SW, O_F2SB, O_F2EW, O_F2EB,
        O_AW, O_AB, O_ASW, O_ASB, O_AEW, O_AEB,
        O_VW, O_VB, O_VSW, O_VSB, O_VEW, O_VEB };
    static const int conv_n[38] = {
        40000, 0, 0, 1600, 4096, 2048, 2048, 128, 262144, 2048, 2048, 128, 8192, 128,
        16384, 128, 16384, 128, 16384, 128,
        16384, 128, 16384, 128, 16384, 128,
        1280, 10, 1280, 10, 1280, 10,
        128, 1, 128, 1, 128, 1 };
    for (int i = 0; i < 38; i++){ ca.src[i] = d_in[i]; ca.off[i] = conv_o[i]; ca.n[i] = conv_n[i]; }
    k_convert<<<dim3(128, 38), 256, 0, stream>>>(ca, ws);

    k_fold<<<dim3(8, 4), 256, 0, stream>>>(ws);
    k_noisy<<<dim3(64, 8), 256, 0, stream>>>(ws);
    k_w2b<<<1024, 256, 0, stream>>>(ws);
    k_zpad<<<24, 256, 0, stream>>>(ws);

    // ---- RGAT layer 1 (fused per-node) ----
    k_node1<<<20000, 128, 0, stream>>>(ei, et, ws);

    // ---- RGAT layer 2 ----
    k_xw2_mfma<<<dim3(157, 16), 256, 0, stream>>>(ws);
    k_aqk<<<1250, 256, 0, stream>>>(ws);
    k_node2<<<20000, 128, 0, stream>>>(ei, et, ws);

    // ---- head ----
    k_pool<<<200, 128, 0, stream>>>(ws);
    k_cosz<<<1600, 128, 0, stream>>>(ws);
    k_ff<<<1600, 128, 0, stream>>>(ws, O_Z0, O_CF1W, O_CF1B, O_Z1);
    k_ff<<<1600, 128, 0, stream>>>(ws, O_Z1, O_CF2W, O_CF2B, O_Z2);
    k_head<<<1600, 64, 0, stream>>>(ws, d_out, d_in[3]);
}

// Round 5
// 252.905 us; speedup vs baseline: 2.6752x; 1.0363x over previous
//
#include <hip/hip_runtime.h>
#include <hip/hip_bf16.h>

// ---------------- problem constants ----------------
constexpr long NN = 20000;   // nodes
constexpr long NE = 160000;  // edges
constexpr long BB = 200;     // graphs
constexpr long TT = 8;       // taus
constexpr long GN = 100;     // nodes per graph

// ---------------- ws layout (f32 element offsets) ----------------
constexpr long O_FLAG = 0;                                      // int mode flag
constexpr long O_X    = 16;                 constexpr long N_X   = 40000;
constexpr long O_TAU  = O_X + N_X;          constexpr long N_TAU = 1600;
constexpr long O_W1   = O_TAU + N_TAU;      constexpr long N_W1  = 4096;
constexpr long O_Q1   = O_W1 + N_W1;        constexpr long N_Q   = 2048;
constexpr long O_K1   = O_Q1 + N_Q;
constexpr long O_B1   = O_K1 + N_Q;         constexpr long N_B   = 128;
constexpr long O_W2   = O_B1 + N_B;         constexpr long N_W2  = 262144;
constexpr long O_Q2   = O_W2 + N_W2;
constexpr long O_K2   = O_Q2 + N_Q;
constexpr long O_B2   = O_K2 + N_Q;
constexpr long O_CW   = O_B2 + N_B;         constexpr long N_CW  = 8192;
constexpr long O_CB   = O_CW + N_CW;
constexpr long O_F1W  = O_CB + N_B;         constexpr long N_FW  = 16384;
constexpr long O_F1B  = O_F1W + N_FW;
constexpr long O_F1SW = O_F1B + N_B;
constexpr long O_F1SB = O_F1SW + N_FW;
constexpr long O_F1EW = O_F1SB + N_B;
constexpr long O_F1EB = O_F1EW + N_FW;
constexpr long O_F2W  = O_F1EB + N_B;
constexpr long O_F2B  = O_F2W + N_FW;
constexpr long O_F2SW = O_F2B + N_B;
constexpr long O_F2SB = O_F2SW + N_FW;
constexpr long O_F2EW = O_F2SB + N_B;
constexpr long O_F2EB = O_F2EW + N_FW;
constexpr long O_AW   = O_F2EB + N_B;       constexpr long N_AW  = 1280;
constexpr long O_AB   = O_AW + N_AW;        constexpr long N_AB  = 16;  // 10 used
constexpr long O_ASW  = O_AB + N_AB;
constexpr long O_ASB  = O_ASW + N_AW;
constexpr long O_AEW  = O_ASB + N_AB;
constexpr long O_AEB  = O_AEW + N_AW;
constexpr long O_VW   = O_AEB + N_AB;       constexpr long N_VW  = 128;
constexpr long O_VB   = O_VW + N_VW;        constexpr long N_VB  = 16;  // 1 used
constexpr long O_VSW  = O_VB + N_VB;
constexpr long O_VSB  = O_VSW + N_VW;
constexpr long O_VEW  = O_VSB + N_VB;
constexpr long O_VEB  = O_VEW + N_VW;
// derived
constexpr long O_WQ1  = O_VEB + N_VB;       // [4][2][4] = 32  (r*8 + i*4 + h)
constexpr long O_WK1  = O_WQ1 + 32;
constexpr long O_WQ2  = O_WK1 + 32;         // [4][128][4] = 2048
constexpr long O_WK2  = O_WQ2 + 2048;
constexpr long O_CF1W = O_WK2 + 2048;       // combined noisy weights
constexpr long O_CF1B = O_CF1W + N_FW;
constexpr long O_CF2W = O_CF1B + N_B;
constexpr long O_CF2B = O_CF2W + N_FW;
constexpr long O_CAW  = O_CF2B + N_B;
constexpr long O_CAB  = O_CAW + N_AW;
constexpr long O_CVW  = O_CAB + N_AB;
constexpr long O_CVB  = O_CVW + N_VW;
constexpr long O_AL1  = O_CVB + N_VB;       // (spacer, unused)
constexpr long O_AL2  = O_AL1 + NE*4;
constexpr long O_H1   = O_AL2 + NE*4;       // [N][128]
constexpr long O_H2   = O_H1 + NN*128;
constexpr long O_G    = O_H2 + NN*128;      // [200][128]
constexpr long O_Z0   = O_G + BB*128;       // [1600][128] (unused after tail fusion)
constexpr long O_Z1   = O_Z0 + BB*TT*128;
constexpr long O_Z2   = O_Z1 + BB*TT*128;
// CSR region
constexpr long O_AGG1 = O_Z2 + BB*TT*128;
constexpr long O_DEG  = O_AGG1;             // [NN] int
constexpr long O_CUR  = O_DEG + NN;         // [NN] int
constexpr long O_ROWP = O_CUR + NN;         // [NN+1] int (+pad)
constexpr long O_PERM = O_ROWP + NN + 8;    // [NE] int
constexpr long O_AGG2 = O_AGG1 + NN*128;
constexpr long O_DEN1 = O_AGG2 + NN*128;
constexpr long O_DEN2 = O_DEN1 + NN*4;
constexpr long O_AMAX1= O_DEN2 + NN*4;
constexpr long O_AMAX2= O_AMAX1 + NN*4;
// bf16 xw2 table [N][4][512] — inner 512 now ordered d*4+h (viewed as u16)
constexpr long O_XW2  = O_AMAX2 + NN*4;
constexpr long O_END_TABLE = O_XW2 + (NN*4*512)/2;
// MFMA-path extras
constexpr long MPAD   = 20096;
constexpr long O_H1B  = O_END_TABLE;                  // [20096][128] bf16
constexpr long O_W2BT = O_H1B + (MPAD*128)/2;         // [2048][128] bf16, row-permuted
constexpr long O_END2 = O_W2BT + (2048L*128)/2;
// AQ/AK tables: [N][16] f32, idx = r*4+h
constexpr long O_AQ   = O_END2;
constexpr long O_AK   = O_AQ + NN*16;
constexpr long O_END3 = O_AK + NN*16;

constexpr int EMAX = 128;

#define DEVFN __device__ __forceinline__

typedef __attribute__((ext_vector_type(8))) short bf16x8;
typedef __attribute__((ext_vector_type(4))) float f32x4;
typedef __attribute__((ext_vector_type(4))) unsigned short u16x4;

DEVFN float selu_f(float x){ return 1.0507009873554805f * (x > 0.f ? x : 1.6732632423543772f * expm1f(x)); }
DEVFN float lrelu_f(float x){ return x >= 0.f ? x : 0.2f * x; }
DEVFN float bf2f(unsigned short u){ return __uint_as_float(((unsigned)u) << 16); }

// ---------------- mode detection ----------------
__global__ void k_detect(const unsigned short* taus_u16, int* flag){
    if (threadIdx.x == 0){
        int bf = 1;
        for (int i = 0; i < 128; i++){
            if (taus_u16[i] > 0x3F80u){ bf = 0; break; }
        }
        *flag = bf;
    }
}

// ---------------- convert all float inputs to f32 in ws ----------------
struct ConvArgs { const void* src[38]; long off[38]; int n[38]; };

__global__ void k_convert(ConvArgs a, float* ws){
    int arr = blockIdx.y;
    long off = a.off[arr];
    if (off < 0) return;
    const void* s = a.src[arr];
    int n = a.n[arr];
    int bf = ((const int*)ws)[0];
    for (int i = blockIdx.x*blockDim.x + threadIdx.x; i < n; i += gridDim.x*blockDim.x){
        float v;
        if (bf){ unsigned short u = ((const unsigned short*)s)[i]; v = bf2f(u); }
        else   { v = ((const float*)s)[i]; }
        ws[off + i] = v;
    }
}

// ---------------- CSR build ----------------
__global__ void k_hist(const int* ei, float* ws){
    long e = (long)blockIdx.x*blockDim.x + threadIdx.x;
    if (e >= NE) return;
    atomicAdd((int*)(ws + O_DEG) + ei[NE + e], 1);
}

__global__ void k_scan(float* ws){
    const int* deg = (const int*)(ws + O_DEG);
    int* rowp = (int*)(ws + O_ROWP);
    __shared__ int part[256];
    int tid = threadIdx.x;
    int base = tid * 79;
    int n = 0; if (base < NN) n = min(79, (int)NN - base);
    int s = 0;
    for (int i = 0; i < n; i++) s += deg[base + i];
    part[tid] = s;
    __syncthreads();
    if (tid == 0){
        int acc = 0;
        for (int i = 0; i < 256; i++){ int t = part[i]; part[i] = acc; acc += t; }
    }
    __syncthreads();
    int acc = part[tid];
    for (int i = 0; i < n; i++){ rowp[base + i] = acc; acc += deg[base + i]; }
    if (tid == 0) rowp[NN] = (int)NE;
}

__global__ void k_scatter(const int* ei, float* ws){
    long e = (long)blockIdx.x*blockDim.x + threadIdx.x;
    if (e >= NE) return;
    int dst = ei[NE + e];
    int pos = atomicAdd((int*)(ws + O_CUR) + dst, 1);
    ((int*)(ws + O_PERM))[((const int*)(ws + O_ROWP))[dst] + pos] = (int)e;
}

// ---------------- fused prep: fold + noisy + w2b + zpad ----------------
__global__ void k_prep(float* ws){
    int phase = blockIdx.y;
    int idx = blockIdx.x*blockDim.x + threadIdx.x;
    if (phase == 0){
        // fold: 0..31 WQ1, 32..63 WK1, 64..2111 WQ2, 2112..4159 WK2
        if (idx >= 4160) return;
        long wsrc, qsrc, dst; int ri, h;
        if (idx < 64){
            int t = idx & 31; h = t & 3; ri = t >> 2;
            wsrc = O_W1 + (long)ri*512;
            qsrc = (idx < 32) ? O_Q1 : O_K1;
            dst  = ((idx < 32) ? O_WQ1 : O_WK1) + t;
        } else {
            int t = (idx - 64) & 2047; h = t & 3; ri = t >> 2;
            wsrc = O_W2 + (long)ri*512;
            qsrc = (idx < 2112) ? O_Q2 : O_K2;
            dst  = ((idx < 2112) ? O_WQ2 : O_WK2) + t;
        }
        const float* W = ws + wsrc;
        const float* Q = ws + qsrc;
        float s = 0.f;
        for (int o = 0; o < 512; o++) s += W[o] * Q[o*4 + h];
        ws[dst] = s;
    } else if (phase == 1){
        // noisy combine, flattened
        const long tw[8] = {O_F1W,O_F2W,O_AW,O_VW, O_F1B,O_F2B,O_AB,O_VB};
        const long ts[8] = {O_F1SW,O_F2SW,O_ASW,O_VSW, O_F1SB,O_F2SB,O_ASB,O_VSB};
        const long te[8] = {O_F1EW,O_F2EW,O_AEW,O_VEW, O_F1EB,O_F2EB,O_AEB,O_VEB};
        const long td[8] = {O_CF1W,O_CF2W,O_CAW,O_CVW, O_CF1B,O_CF2B,O_CAB,O_CVB};
        const int  tn[8] = {16384,16384,1280,128, 128,128,10,1};
        const int  tb[8] = {0,16384,32768,34048, 34176,34304,34432,34442}; // prefix
        int total = 34443;
        for (int i = idx; i < total; i += gridDim.x*blockDim.x){
            int t = 0;
            #pragma unroll
            for (int q = 1; q < 8; q++) if (i >= tb[q]) t = q;
            int j = i - tb[t];
            if (j < tn[t]) ws[td[t] + j] = ws[tw[t] + j] + ws[ts[t] + j]*ws[te[t] + j];
        }
    } else if (phase == 2){
        // W2 -> Bt row-permuted bf16: row n' = r*512 + d*4 + h holds W2[r][:,h*128+d]
        if (idx >= 262144) return;
        int np = idx & 2047, k = idx >> 11;
        int r = np >> 9, q = np & 511, d = q >> 2, h = q & 3;
        float v = ws[O_W2 + (long)r*65536 + (long)k*512 + h*128 + d];
        ((__hip_bfloat16*)(ws + O_W2BT))[(long)np*128 + k] = __float2bfloat16(v);
    } else {
        // zero H1B pad rows
        if (idx < 6144) ws[O_H1B + (20000L*128)/2 + idx] = 0.f;
    }
}

// ---------------- fused layer-1 node kernel ----------------
__global__ void k_node1(const int* ei, const int* et, float* ws){
    __shared__ float wqk[64];
    __shared__ float alc[EMAX][4];
    __shared__ float xsc[EMAX][2];
    __shared__ int   rtc[EMAX];
    __shared__ float sacc[4][4][2];
    __shared__ float den[4], amax[4];
    __shared__ float mred[2][4];
    int n = blockIdx.x, tid = threadIdx.x;
    const int* rowp = (const int*)(ws + O_ROWP);
    const int* perm = (const int*)(ws + O_PERM);
    int e0 = rowp[n], deg = rowp[n+1] - e0;
    if (tid < 64) wqk[tid] = ws[O_WQ1 + tid];
    if (tid < 32) ((float*)sacc)[tid] = 0.f;
    if (tid < 4) den[tid] = 0.f;
    float xd0 = ws[O_X + (long)n*2], xd1 = ws[O_X + (long)n*2 + 1];
    __syncthreads();
    float mx[4] = {-3.0e38f,-3.0e38f,-3.0e38f,-3.0e38f};
    for (int j0 = 0; j0 < deg; j0 += 128){
        int j = j0 + tid;
        if (j < deg){
            int e = perm[e0 + j];
            int src = ei[e], rt = et[e];
            float xs0 = ws[O_X + (long)src*2], xs1 = ws[O_X + (long)src*2 + 1];
            const float* Wq = wqk + rt*8;
            const float* Wk = wqk + 32 + rt*8;
            #pragma unroll
            for (int h = 0; h < 4; h++){
                float a = lrelu_f(xd0*Wq[h] + xd1*Wq[4+h] + xs0*Wk[h] + xs1*Wk[4+h]);
                if (j < EMAX) alc[j][h] = a;
                mx[h] = fmaxf(mx[h], a);
            }
            if (j < EMAX){ xsc[j][0] = xs0; xsc[j][1] = xs1; rtc[j] = rt; }
        }
    }
    #pragma unroll
    for (int off = 32; off > 0; off >>= 1)
        #pragma unroll
        for (int h = 0; h < 4; h++) mx[h] = fmaxf(mx[h], __shfl_xor(mx[h], off));
    if ((tid & 63) == 0)
        #pragma unroll
        for (int h = 0; h < 4; h++) mred[tid >> 6][h] = mx[h];
    __syncthreads();
    if (tid < 4) amax[tid] = fmaxf(mred[0][tid], mred[1][tid]);
    __syncthreads();
    for (int j0 = 0; j0 < deg; j0 += 128){
        int j = j0 + tid;
        if (j < deg){
            float al[4], xs0, xs1; int rt;
            if (j < EMAX){
                #pragma unroll
                for (int h = 0; h < 4; h++) al[h] = alc[j][h];
                xs0 = xsc[j][0]; xs1 = xsc[j][1]; rt = rtc[j];
            } else {
                int e = perm[e0 + j];
                int src = ei[e]; rt = et[e];
                xs0 = ws[O_X + (long)src*2]; xs1 = ws[O_X + (long)src*2 + 1];
                const float* Wq = wqk + rt*8;
                const float* Wk = wqk + 32 + rt*8;
                #pragma unroll
                for (int h = 0; h < 4; h++)
                    al[h] = lrelu_f(xd0*Wq[h] + xd1*Wq[4+h] + xs0*Wk[h] + xs1*Wk[4+h]);
            }
            #pragma unroll
            for (int h = 0; h < 4; h++){
                float ex = expf(al[h] - amax[h]);
                atomicAdd(&den[h], ex);
                atomicAdd(&sacc[rt][h][0], ex*xs0);
                atomicAdd(&sacc[rt][h][1], ex*xs1);
            }
        }
    }
    __syncthreads();
    int d = tid;
    float rden[4];
    #pragma unroll
    for (int h = 0; h < 4; h++) rden[h] = den[h] > 0.f ? 0.25f/den[h] : 0.f;
    float v = 0.f;
    #pragma unroll
    for (int r = 0; r < 4; r++)
        #pragma unroll
        for (int h = 0; h < 4; h++){
            float w0 = ws[O_W1 + r*1024 +        h*128 + d];
            float w1 = ws[O_W1 + r*1024 + 512  + h*128 + d];
            v += rden[h]*(w0*sacc[r][h][0] + w1*sacc[r][h][1]);
        }
    float out = selu_f(v + ws[O_B1 + d]);
    ws[O_H1 + (long)n*128 + d] = out;
    ((__hip_bfloat16*)(ws + O_H1B))[(long)n*128 + d] = __float2bfloat16(out);
}

// ---------------- AQ/AK tables ----------------
__global__ void k_aqk(float* ws){
    __shared__ float wq[128*16];
    __shared__ float wk[128*16];
    __shared__ float hl[16][129];
    int tid = threadIdx.x;
    long nb = (long)blockIdx.x * 16;
    #pragma unroll
    for (int c = 0; c < 8; c++){
        int idx = tid + c*256;
        int i = idx >> 4, o = idx & 15;
        int r = o >> 2, h = o & 3;
        wq[i*16 + o] = ws[O_WQ2 + r*512 + i*4 + h];
        wk[i*16 + o] = ws[O_WK2 + r*512 + i*4 + h];
        hl[idx >> 7][idx & 127] = ws[O_H1 + nb*128 + idx];
    }
    __syncthreads();
    int j = tid >> 4, o = tid & 15;
    float aq = 0.f, ak = 0.f;
    #pragma unroll 4
    for (int i = 0; i < 128; i++){
        float hv = hl[j][i];
        aq += hv * wq[i*16 + o];
        ak += hv * wk[i*16 + o];
    }
    ws[O_AQ + (nb + j)*16 + o] = aq;
    ws[O_AK + (nb + j)*16 + o] = ak;
}

// ---------------- xw2 = h1 @ W2 via MFMA (B rows pre-permuted) ----------------
__global__ void k_xw2_mfma(float* ws){
    __shared__ __align__(16) unsigned short Ash[128*128];
    __shared__ __align__(16) unsigned short Bsh[128*128];
    const unsigned short* h1b  = (const unsigned short*)(ws + O_H1B);
    const unsigned short* w2bt = (const unsigned short*)(ws + O_W2BT);
    long bm = (long)blockIdx.x * 128;
    long bn = (long)blockIdx.y * 128;
    int tid = threadIdx.x;
    char* Ac = (char*)Ash; char* Bc = (char*)Bsh;
    #pragma unroll
    for (int i = 0; i < 8; i++){
        int c = tid + i*256;
        int row = c >> 4, kb = (c & 15) * 16;
        int off = row*256 + (kb ^ ((row & 7) << 4));
        *(bf16x8*)(Ac + off) = *(const bf16x8*)&h1b [(bm + row)*128 + (c & 15)*8];
        *(bf16x8*)(Bc + off) = *(const bf16x8*)&w2bt[(bn + row)*128 + (c & 15)*8];
    }
    __syncthreads();
    int w = tid >> 6, lane = tid & 63;
    int wm = (w >> 1) * 64, wn = (w & 1) * 64;
    int r16 = lane & 15, kq = lane >> 4;
    f32x4 acc[4][4] = {};
    #pragma unroll
    for (int ks = 0; ks < 4; ks++){
        int kbyte = ks*64 + kq*16;
        bf16x8 a[4], b[4];
        #pragma unroll
        for (int m = 0; m < 4; m++){
            int row = wm + m*16 + r16;
            a[m] = *(const bf16x8*)(Ac + row*256 + (kbyte ^ ((row & 7) << 4)));
        }
        #pragma unroll
        for (int n = 0; n < 4; n++){
            int row = wn + n*16 + r16;
            b[n] = *(const bf16x8*)(Bc + row*256 + (kbyte ^ ((row & 7) << 4)));
        }
        #pragma unroll
        for (int m = 0; m < 4; m++)
            #pragma unroll
            for (int n = 0; n < 4; n++)
                acc[m][n] = __builtin_amdgcn_mfma_f32_16x16x32_bf16(a[m], b[n], acc[m][n], 0, 0, 0);
    }
    __hip_bfloat16* xb = (__hip_bfloat16*)(ws + O_XW2);
    #pragma unroll
    for (int m = 0; m < 4; m++){
        long gr0 = bm + wm + m*16 + kq*4;
        #pragma unroll
        for (int j = 0; j < 4; j++){
            long gr = gr0 + j;
            if (gr < NN){
                #pragma unroll
                for (int n = 0; n < 4; n++){
                    long gc = bn + wn + n*16 + r16;
                    xb[gr*2048 + gc] = __float2bfloat16(acc[m][n][j]);
                }
            }
        }
    }
}

// ---------------- fused layer-2 node kernel (coalesced ushort4 gather) ----------------
__global__ void k_node2(const int* ei, const int* et, float* ws){
    __shared__ float aq[16];
    __shared__ float exc[EMAX][4];
    __shared__ int   esrt[EMAX];
    __shared__ float den[4], amax[4];
    __shared__ float mred[2][4];
    int n = blockIdx.x, tid = threadIdx.x;
    const int* rowp = (const int*)(ws + O_ROWP);
    const int* perm = (const int*)(ws + O_PERM);
    int e0 = rowp[n], deg = rowp[n+1] - e0;
    if (tid < 16) aq[tid] = ws[O_AQ + (long)n*16 + tid];
    if (tid < 4) den[tid] = 0.f;
    __syncthreads();
    float mx[4] = {-3.0e38f,-3.0e38f,-3.0e38f,-3.0e38f};
    for (int j0 = 0; j0 < deg; j0 += 128){
        int j = j0 + tid;
        if (j < deg){
            int e = perm[e0 + j];
            int src = ei[e], rt = et[e];
            float4 k4 = *(const float4*)&ws[O_AK + (long)src*16 + rt*4];
            float al0 = lrelu_f(aq[rt*4+0] + k4.x);
            float al1 = lrelu_f(aq[rt*4+1] + k4.y);
            float al2 = lrelu_f(aq[rt*4+2] + k4.z);
            float al3 = lrelu_f(aq[rt*4+3] + k4.w);
            if (j < EMAX){
                exc[j][0]=al0; exc[j][1]=al1; exc[j][2]=al2; exc[j][3]=al3;
                esrt[j] = src*4 + rt;
            }
            mx[0]=fmaxf(mx[0],al0); mx[1]=fmaxf(mx[1],al1);
            mx[2]=fmaxf(mx[2],al2); mx[3]=fmaxf(mx[3],al3);
        }
    }
    #pragma unroll
    for (int off = 32; off > 0; off >>= 1)
        #pragma unroll
        for (int h = 0; h < 4; h++) mx[h] = fmaxf(mx[h], __shfl_xor(mx[h], off));
    if ((tid & 63) == 0)
        #pragma unroll
        for (int h = 0; h < 4; h++) mred[tid >> 6][h] = mx[h];
    __syncthreads();
    if (tid < 4) amax[tid] = fmaxf(mred[0][tid], mred[1][tid]);
    __syncthreads();
    for (int j0 = 0; j0 < deg; j0 += 128){
        int j = j0 + tid;
        if (j < deg && j < EMAX){
            #pragma unroll
            for (int h = 0; h < 4; h++){
                float ex = expf(exc[j][h] - amax[h]);
                exc[j][h] = ex;
                atomicAdd(&den[h], ex);
            }
        } else if (j < deg){
            int e = perm[e0 + j];
            int src = ei[e], rt = et[e];
            float4 k4 = *(const float4*)&ws[O_AK + (long)src*16 + rt*4];
            float al[4] = {lrelu_f(aq[rt*4+0]+k4.x), lrelu_f(aq[rt*4+1]+k4.y),
                           lrelu_f(aq[rt*4+2]+k4.z), lrelu_f(aq[rt*4+3]+k4.w)};
            #pragma unroll
            for (int h = 0; h < 4; h++) atomicAdd(&den[h], expf(al[h]-amax[h]));
        }
    }
    __syncthreads();
    // pass 3: coalesced gather — table row inner layout is [d][h], thread d reads ushort4
    int d = tid;
    const unsigned short* xw2 = (const unsigned short*)(ws + O_XW2);
    float acc[4] = {0.f,0.f,0.f,0.f};
    for (int j = 0; j < deg; j++){
        float ex[4]; long sr;
        if (j < EMAX){
            ex[0]=exc[j][0]; ex[1]=exc[j][1]; ex[2]=exc[j][2]; ex[3]=exc[j][3];
            sr = esrt[j];
        } else {
            int e = perm[e0 + j];
            int src = ei[e], rt = et[e];
            float4 k4 = *(const float4*)&ws[O_AK + (long)src*16 + rt*4];
            ex[0]=expf(lrelu_f(aq[rt*4+0]+k4.x)-amax[0]);
            ex[1]=expf(lrelu_f(aq[rt*4+1]+k4.y)-amax[1]);
            ex[2]=expf(lrelu_f(aq[rt*4+2]+k4.z)-amax[2]);
            ex[3]=expf(lrelu_f(aq[rt*4+3]+k4.w)-amax[3]);
            sr = (long)src*4 + rt;
        }
        u16x4 v = *(const u16x4*)(xw2 + sr*512 + (d << 2));
        acc[0] += ex[0]*bf2f(v[0]);
        acc[1] += ex[1]*bf2f(v[1]);
        acc[2] += ex[2]*bf2f(v[2]);
        acc[3] += ex[3]*bf2f(v[3]);
    }
    float v = 0.f;
    #pragma unroll
    for (int h = 0; h < 4; h++){
        float rden = den[h] > 0.f ? 0.25f/den[h] : 0.f;
        v += acc[h]*rden;
    }
    ws[O_H2 + (long)n*128 + d] = selu_f(v + ws[O_B2 + d]);
}

// ---------------- global add pool ----------------
__global__ void k_pool(float* ws){
    int b = blockIdx.x, d = threadIdx.x;
    float s = 0.f;
    for (int j = 0; j < GN; j++) s += ws[O_H2 + ((long)b*GN + j)*128 + d];
    ws[O_G + (long)b*128 + d] = s;
}

// ---------------- fused tail: cos embed + z + ff1 + ff2 + dueling head ----------------
__global__ void k_tail(float* ws, void* d_out, const void* taus_raw){
    __shared__ float cs[64];
    __shared__ float row0[128], row1[128], row2[128];
    __shared__ float advs[12];
    int bt = blockIdx.x, t = threadIdx.x;
    int b = bt >> 3;
    if (t < 64){
        float tau = ws[O_TAU + bt];
        cs[t] = cosf(tau * (3.14159265358979323846f * (float)(t + 1)));
    }
    __syncthreads();
    // z0 = g * relu(cos @ cw^T + cb)
    {
        const float* cw = ws + O_CW + (long)t*64;
        float s = ws[O_CB + t];
        for (int c = 0; c < 64; c++) s += cs[c]*cw[c];
        s = fmaxf(s, 0.f);
        row0[t] = ws[O_G + (long)b*128 + t] * s;
    }
    __syncthreads();
    // ff1
    {
        const float* W = ws + O_CF1W + (long)t*128;
        float s = ws[O_CF1B + t];
        for (int i = 0; i < 128; i++) s += row0[i]*W[i];
        row1[t] = selu_f(s);
    }
    __syncthreads();
    // ff2
    {
        const float* W = ws + O_CF2W + (long)t*128;
        float s = ws[O_CF2B + t];
        for (int i = 0; i < 128; i++) s += row1[i]*W[i];
        row2[t] = selu_f(s);
    }
    __syncthreads();
    if (t < 11){
        const float* W = (t < 10) ? (ws + O_CAW + (long)t*128) : (ws + O_CVW);
        float s = (t < 10) ? ws[O_CAB + t] : ws[O_CVB];
        for (int i = 0; i < 128; i++) s += row2[i]*W[i];
        advs[t] = s;
    }
    __syncthreads();
    if (t == 0){
        float m = 0.f;
        #pragma unroll
        for (int a = 0; a < 10; a++) m += advs[a];
        m *= 0.1f;
        float val = advs[10];
        int bf = ((const int*)ws)[0];
        if (bf){
            __hip_bfloat16* out = (__hip_bfloat16*)d_out;
            for (int a = 0; a < 10; a++) out[(long)bt*10 + a] = __float2bfloat16(val + advs[a] - m);
            ((unsigned short*)d_out)[16000 + bt] = ((const unsigned short*)taus_raw)[bt];
        } else {
            float* out = (float*)d_out;
            for (int a = 0; a < 10; a++) out[(long)bt*10 + a] = val + advs[a] - m;
            out[16000 + bt] = ((const float*)taus_raw)[bt];
        }
    }
}

// ---------------- launch ----------------
extern "C" void kernel_launch(void* const* d_in, const int* in_sizes, int n_in,
                              void* d_out, int out_size, void* d_ws, size_t ws_size,
                              hipStream_t stream){
    (void)in_sizes; (void)n_in; (void)out_size; (void)ws_size;
    float* ws = (float*)d_ws;
    const int* ei = (const int*)d_in[1];
    const int* et = (const int*)d_in[2];

    hipMemsetAsync(ws + O_DEG, 0, (size_t)(2*NN)*4, stream);

    k_detect<<<1, 64, 0, stream>>>((const unsigned short*)d_in[3], (int*)d_ws);

    k_hist<<<625, 256, 0, stream>>>(ei, ws);
    k_scan<<<1, 256, 0, stream>>>(ws);
    k_scatter<<<625, 256, 0, stream>>>(ei, ws);

    ConvArgs ca;
    static const long conv_o[38] = {
        O_X, -1, -1, O_TAU, O_W1, O_Q1, O_K1, O_B1, O_W2, O_Q2, O_K2, O_B2, O_CW, O_CB,
        O_F1W, O_F1B, O_F1SW, O_F1SB, O_F1EW, O_F1EB,
        O_F2W, O_F2B, O_F2SW, O_F2SB, O_F2EW, O_F2EB,
        O_AW, O_AB, O_ASW, O_ASB, O_AEW, O_AEB,
        O_VW, O_VB, O_VSW, O_VSB, O_VEW, O_VEB };
    static const int conv_n[38] = {
        40000, 0, 0, 1600, 4096, 2048, 2048, 128, 262144, 2048, 2048, 128, 8192, 128,
        16384, 128, 16384, 128, 16384, 128,
        16384, 128, 16384, 128, 16384, 128,
        1280, 10, 1280, 10, 1280, 10,
        128, 1, 128, 1, 128, 1 };
    for (int i = 0; i < 38; i++){ ca.src[i] = d_in[i]; ca.off[i] = conv_o[i]; ca.n[i] = conv_n[i]; }
    k_convert<<<dim3(128, 38), 256, 0, stream>>>(ca, ws);

    k_prep<<<dim3(1024, 4), 256, 0, stream>>>(ws);

    // ---- RGAT layer 1 ----
    k_node1<<<20000, 128, 0, stream>>>(ei, et, ws);

    // ---- RGAT layer 2 ----
    k_xw2_mfma<<<dim3(157, 16), 256, 0, stream>>>(ws);
    k_aqk<<<1250, 256, 0, stream>>>(ws);
    k_node2<<<20000, 128, 0, stream>>>(ei, et, ws);

    // ---- head ----
    k_pool<<<200, 128, 0, stream>>>(ws);
    k_tail<<<1600, 128, 0, stream>>>(ws, d_out, d_in[3]);
}